// Round 12
// baseline (66.256 us; speedup 1.0000x reference)
//
#include <hip/hip_runtime.h>
#include <hip/hip_cooperative_groups.h>

namespace cg = cooperative_groups;

typedef float  f32x4 __attribute__((ext_vector_type(4)));
typedef short  s16x8 __attribute__((ext_vector_type(8)));
typedef ushort u16x8 __attribute__((ext_vector_type(8)));

constexpr int D  = 128;
constexpr int K  = 512;
constexpr int O  = 256;
constexpr int NT = 256;
constexpr float NL2E = -1.44269504088896340736f;  // -log2(e)

__device__ __forceinline__ ushort f2bf(float f) {
    uint u = __builtin_bit_cast(uint, f);
    return (ushort)((u + 0x7FFFu + ((u >> 16) & 1u)) >> 16);
}
__device__ __forceinline__ float bf2f(ushort h) {
    return __builtin_bit_cast(float, ((uint)h) << 16);
}

constexpr int PP = 40;   // Ps row stride in ushorts

// ================= cooperative single-dispatch kernel =================
// Phase 1: convert operands to frag-ordered bf16 in ws (608 jobs over 512
// half-blocks, wave-local reductions only). grid.sync(). Phase 2: round-11
// main body verbatim (2 row-panels per wave, wave = K-eighth).
__global__ __launch_bounds__(512, 1)
void rbf_coop(const float* __restrict__ x, const float* __restrict__ cen,
              const float* __restrict__ ls, const float* __restrict__ w,
              ushort* __restrict__ Xh, ushort* __restrict__ Xl,
              ushort* __restrict__ Ch, ushort* __restrict__ Cl,
              ushort* __restrict__ Wf, float* __restrict__ xs2,
              float2* __restrict__ ecs, float* __restrict__ out, int N)
{
    __shared__ ushort PsA[8][16][PP];     // 10.2 KB
    __shared__ ushort PsB[8][16][PP];     // 10.2 KB
    __shared__ float  Acc[2][32][O + 4];  // 66.6 KB
    __shared__ float  Ls[8][32];          // 1 KB

    const int tt = threadIdx.x;

    // ---------- phase 1: operand conversion into ws ----------
    {
        const int hb   = blockIdx.x * 2 + (tt >> 8);  // half-block id 0..511
        const int tloc = tt & 255;
        const int wj = (tloc >> 6);      // wave-in-job 0..3
        const int lj = tloc & 63;
        const int rr = lj >> 4;          // row-in-group 0..3
        const int cb = lj & 15;          // col block (8 cols)
        for (int job = hb; job < 608; job += 512) {
            if (job < 544) {
                // X panel (job<512) or C panel (512..543): 16 rows x 128 cols
                const bool isX = job < 512;
                const int panel = isX ? job : job - 512;
                const float* src = isX ? x : cen;
                ushort* dh = isX ? Xh : Ch;
                ushort* dl = isX ? Xl : Cl;
                const int row = panel * 16 + wj * 4 + rr;
                const float* p = src + (size_t)row * D + cb * 8;
                float4 v0 = *(const float4*)p, v1 = *(const float4*)(p + 4);
                float f[8] = {v0.x, v0.y, v0.z, v0.w, v1.x, v1.y, v1.z, v1.w};
                u16x8 h, l;
                float s = 0.f;
#pragma unroll
                for (int j = 0; j < 8; ++j) {
                    s = fmaf(f[j], f[j], s);
                    ushort hb2 = f2bf(f[j]);
                    h[j] = hb2;
                    l[j] = f2bf(f[j] - bf2f(hb2));
                }
                // frag-order: chunk (panel*4+q)*64+lp holds row panel*16+(lp&15),
                // col q*32+(lp>>4)*8+j
                const int q  = cb >> 2;
                const int lp = (wj * 4 + rr) + (cb & 3) * 16;
                const size_t c = ((size_t)panel * 4 + q) * 64 + lp;
                *(u16x8*)&dh[c * 8] = h;
                *(u16x8*)&dl[c * 8] = l;
                // row norm: reduce over the 16 cb-lanes (wave-local)
                s += __shfl_xor(s, 1); s += __shfl_xor(s, 2);
                s += __shfl_xor(s, 4); s += __shfl_xor(s, 8);
                if (cb == 0) {
                    if (isX) {
                        xs2[row] = s;
                    } else {
                        float e = __expf(2.0f * ls[row]);
                        ecs[row] = make_float2(NL2E * e, NL2E * e * s);
                    }
                }
            } else {
                // W job (544..607): 256 threads x 8 elems, frag-ordered
                const int c0 = (job - 544) * 256 + tloc;
                const int ln = c0 & 63, ot = (c0 >> 6) & 15, ks = c0 >> 10;
                const int o  = ot * 16 + (ln & 15);
                const int kb = ks * 32 + (ln >> 4) * 8;
                const float* p = w + (size_t)o * K + kb;
                float4 v0 = *(const float4*)p, v1 = *(const float4*)(p + 4);
                u16x8 h;
                h[0] = f2bf(v0.x); h[1] = f2bf(v0.y); h[2] = f2bf(v0.z); h[3] = f2bf(v0.w);
                h[4] = f2bf(v1.x); h[5] = f2bf(v1.y); h[6] = f2bf(v1.z); h[7] = f2bf(v1.w);
                *(u16x8*)&Wf[(size_t)c0 * 8] = h;
            }
        }
    }

    cg::this_grid().sync();

    // ---------- phase 2: round-11 main body ----------
    const int lane = tt & 63, wv = tt >> 6;   // wv 0..7
    const int l15 = lane & 15, l4 = lane >> 4;
    const int pan = blockIdx.x;               // 32-row panel index

    s16x8 xhA[4], xlA[4], xhB[4], xlB[4];
    {
        const size_t baseA = ((size_t)(pan * 2) * 4) * 64 + lane;
        const size_t baseB = ((size_t)(pan * 2 + 1) * 4) * 64 + lane;
#pragma unroll
        for (int q = 0; q < 4; ++q) {
            xhA[q] = *(const s16x8*)&Xh[(baseA + q * 64) * 8];
            xlA[q] = *(const s16x8*)&Xl[(baseA + q * 64) * 8];
            xhB[q] = *(const s16x8*)&Xh[(baseB + q * 64) * 8];
            xlB[q] = *(const s16x8*)&Xl[(baseB + q * 64) * 8];
        }
    }
    const float xs2A = xs2[pan * 32 + l15];
    const float xs2B = xs2[pan * 32 + 16 + l15];

    f32x4 oaccA[16], oaccB[16];
#pragma unroll
    for (int i = 0; i < 16; ++i) {
        oaccA[i] = (f32x4){0.f, 0.f, 0.f, 0.f};
        oaccB[i] = (f32x4){0.f, 0.f, 0.f, 0.f};
    }
    float LpA = 0.f, LpB = 0.f;

    const int kw = wv * 64;

#pragma unroll
    for (int s = 0; s < 2; ++s) {
        const int kslab = (kw >> 5) + s;
        const ushort* wbase = &Wf[(((size_t)kslab * 16) * 64 + lane) * 8];

#pragma unroll
        for (int bt = 0; bt < 2; ++bt) {
            const size_t kt16 = (size_t)(kw >> 4) + s * 2 + bt;
            s16x8 ch[4], cl[4];
#pragma unroll
            for (int q = 0; q < 4; ++q) {
                const size_t cc = ((kt16 * 4 + q) * 64 + lane) * 8;
                ch[q] = *(const s16x8*)&Ch[cc];
                cl[q] = *(const s16x8*)&Cl[cc];
            }
            f32x4 gA = (f32x4){0.f,0.f,0.f,0.f};
            f32x4 gB = (f32x4){0.f,0.f,0.f,0.f};
#pragma unroll
            for (int q = 0; q < 4; ++q) {
                gA = __builtin_amdgcn_mfma_f32_16x16x32_bf16(ch[q], xhA[q], gA, 0, 0, 0);
                gB = __builtin_amdgcn_mfma_f32_16x16x32_bf16(ch[q], xhB[q], gB, 0, 0, 0);
            }
#pragma unroll
            for (int q = 0; q < 4; ++q) {
                gA = __builtin_amdgcn_mfma_f32_16x16x32_bf16(ch[q], xlA[q], gA, 0, 0, 0);
                gB = __builtin_amdgcn_mfma_f32_16x16x32_bf16(ch[q], xlB[q], gB, 0, 0, 0);
            }
#pragma unroll
            for (int q = 0; q < 4; ++q) {
                gA = __builtin_amdgcn_mfma_f32_16x16x32_bf16(cl[q], xhA[q], gA, 0, 0, 0);
                gB = __builtin_amdgcn_mfma_f32_16x16x32_bf16(cl[q], xhB[q], gB, 0, 0, 0);
            }

            const int kbase = kw + s * 32 + bt * 16 + l4 * 4;
            float4 e0 = *(const float4*)&ecs[kbase];
            float4 e1 = *(const float4*)&ecs[kbase + 2];
            {
                float p0 = exp2f(fmaf(e0.x, fmaf(-2.f, gA[0], xs2A), e0.y));
                float p1 = exp2f(fmaf(e0.z, fmaf(-2.f, gA[1], xs2A), e0.w));
                float p2 = exp2f(fmaf(e1.x, fmaf(-2.f, gA[2], xs2A), e1.y));
                float p3 = exp2f(fmaf(e1.z, fmaf(-2.f, gA[3], xs2A), e1.w));
                LpA += (p0 + p1) + (p2 + p3);
                uint u0 = (uint)f2bf(p0) | ((uint)f2bf(p1) << 16);
                uint u1 = (uint)f2bf(p2) | ((uint)f2bf(p3) << 16);
                *(uint2*)&PsA[wv][l15][bt * 16 + l4 * 4] = make_uint2(u0, u1);
            }
            {
                float p0 = exp2f(fmaf(e0.x, fmaf(-2.f, gB[0], xs2B), e0.y));
                float p1 = exp2f(fmaf(e0.z, fmaf(-2.f, gB[1], xs2B), e0.w));
                float p2 = exp2f(fmaf(e1.x, fmaf(-2.f, gB[2], xs2B), e1.y));
                float p3 = exp2f(fmaf(e1.z, fmaf(-2.f, gB[3], xs2B), e1.w));
                LpB += (p0 + p1) + (p2 + p3);
                uint u0 = (uint)f2bf(p0) | ((uint)f2bf(p1) << 16);
                uint u1 = (uint)f2bf(p2) | ((uint)f2bf(p3) << 16);
                *(uint2*)&PsB[wv][l15][bt * 16 + l4 * 4] = make_uint2(u0, u1);
            }
        }

        s16x8 paA = *(const s16x8*)&PsA[wv][l15][l4 * 8];
        s16x8 paB = *(const s16x8*)&PsB[wv][l15][l4 * 8];
#pragma unroll
        for (int ot = 0; ot < 16; ++ot) {
            s16x8 bfr = *(const s16x8*)&wbase[(size_t)ot * 64 * 8];
            oaccA[ot] = __builtin_amdgcn_mfma_f32_16x16x32_bf16(paA, bfr, oaccA[ot], 0, 0, 0);
            oaccB[ot] = __builtin_amdgcn_mfma_f32_16x16x32_bf16(paB, bfr, oaccB[ot], 0, 0, 0);
        }
    }

    {
        float vA = LpA, vB = LpB;
        vA += __shfl_xor(vA, 16);  vA += __shfl_xor(vA, 32);
        vB += __shfl_xor(vB, 16);  vB += __shfl_xor(vB, 32);
        if (lane < 16) {
            Ls[wv][lane]      = vA;
            Ls[wv][16 + lane] = vB;
        }
    }

    if (wv < 2) {
#pragma unroll
        for (int ot = 0; ot < 16; ++ot)
#pragma unroll
            for (int r = 0; r < 4; ++r) {
                Acc[wv][l4 * 4 + r][ot * 16 + l15]      = oaccA[ot][r];
                Acc[wv][16 + l4 * 4 + r][ot * 16 + l15] = oaccB[ot][r];
            }
    }
    __syncthreads();
    if (wv == 2 || wv == 3) {
#pragma unroll
        for (int ot = 0; ot < 16; ++ot)
#pragma unroll
            for (int r = 0; r < 4; ++r) {
                Acc[wv - 2][l4 * 4 + r][ot * 16 + l15]      += oaccA[ot][r];
                Acc[wv - 2][16 + l4 * 4 + r][ot * 16 + l15] += oaccB[ot][r];
            }
    }
    __syncthreads();
    if (wv == 4 || wv == 5) {
#pragma unroll
        for (int ot = 0; ot < 16; ++ot)
#pragma unroll
            for (int r = 0; r < 4; ++r) {
                Acc[wv - 4][l4 * 4 + r][ot * 16 + l15]      += oaccA[ot][r];
                Acc[wv - 4][16 + l4 * 4 + r][ot * 16 + l15] += oaccB[ot][r];
            }
    }
    __syncthreads();
    if (wv >= 6) {
#pragma unroll
        for (int ot = 0; ot < 16; ++ot)
#pragma unroll
            for (int r = 0; r < 4; ++r) {
                Acc[wv - 6][l4 * 4 + r][ot * 16 + l15]      += oaccA[ot][r];
                Acc[wv - 6][16 + l4 * 4 + r][ot * 16 + l15] += oaccB[ot][r];
            }
    }
    __syncthreads();

    {
        const int n  = tt >> 4;
        const int c0 = (tt & 15) * 16;
        float inv = 1.0f / (Ls[0][n] + Ls[1][n] + Ls[2][n] + Ls[3][n] +
                            Ls[4][n] + Ls[5][n] + Ls[6][n] + Ls[7][n] + 1e-9f);
        float* po = &out[(size_t)(pan * 32 + n) * O + c0];
#pragma unroll
        for (int j = 0; j < 4; ++j) {
            float4 a = *(const float4*)&Acc[0][n][c0 + j * 4];
            float4 b = *(const float4*)&Acc[1][n][c0 + j * 4];
            float4 o;
            o.x = (a.x + b.x) * inv;
            o.y = (a.y + b.y) * inv;
            o.z = (a.z + b.z) * inv;
            o.w = (a.w + b.w) * inv;
            *(float4*)(po + j * 4) = o;
        }
    }
}

// ================= fallback path 1: round-11 two-kernel pipeline =================
__global__ __launch_bounds__(NT)
void rbf_prep(const float* __restrict__ x, const float* __restrict__ cen,
              const float* __restrict__ ls, const float* __restrict__ w,
              ushort* __restrict__ Xh, ushort* __restrict__ Xl,
              ushort* __restrict__ Ch, ushort* __restrict__ Cl,
              ushort* __restrict__ Wf, float* __restrict__ xs2,
              float2* __restrict__ ecs, int nxb, int ncb)
{
    __shared__ float red[4][16];
    const int b = blockIdx.x, t = threadIdx.x, lane = t & 63, wq = t >> 6;

    if (b < nxb + ncb) {
        const bool isX  = b < nxb;
        const int panel = isX ? b : (b - nxb);
        const float* src = isX ? x : cen;
        ushort* dh = isX ? Xh : Ch;
        ushort* dl = isX ? Xl : Cl;
        const int row = panel * 16 + (lane & 15);
        const int col = wq * 32 + (lane >> 4) * 8;
        const float* p = src + (size_t)row * D + col;
        float4 v0 = *(const float4*)p, v1 = *(const float4*)(p + 4);
        float f[8] = {v0.x, v0.y, v0.z, v0.w, v1.x, v1.y, v1.z, v1.w};
        u16x8 h, l;
        float s = 0.f;
#pragma unroll
        for (int j = 0; j < 8; ++j) {
            s = fmaf(f[j], f[j], s);
            ushort hb = f2bf(f[j]);
            h[j] = hb;
            l[j] = f2bf(f[j] - bf2f(hb));
        }
        const size_t c = ((size_t)panel * 4 + wq) * 64 + lane;
        *(u16x8*)&dh[c * 8] = h;
        *(u16x8*)&dl[c * 8] = l;
        s += __shfl_xor(s, 16);
        s += __shfl_xor(s, 32);
        if (lane < 16) red[wq][lane] = s;
        __syncthreads();
        if (t < 16) {
            float sum = red[0][t] + red[1][t] + red[2][t] + red[3][t];
            if (isX) {
                xs2[panel * 16 + t] = sum;
            } else {
                int k = panel * 16 + t;
                float e = __expf(2.0f * ls[k]);
                ecs[k] = make_float2(NL2E * e, NL2E * e * sum);
            }
        }
    } else {
        const int c0 = (b - nxb - ncb) * NT + t;
        const int ln = c0 & 63, ot = (c0 >> 6) & 15, ks = c0 >> 10;
        const int o  = ot * 16 + (ln & 15);
        const int kb = ks * 32 + (ln >> 4) * 8;
        const float* p = w + (size_t)o * K + kb;
        float4 v0 = *(const float4*)p, v1 = *(const float4*)(p + 4);
        u16x8 h;
        h[0] = f2bf(v0.x); h[1] = f2bf(v0.y); h[2] = f2bf(v0.z); h[3] = f2bf(v0.w);
        h[4] = f2bf(v1.x); h[5] = f2bf(v1.y); h[6] = f2bf(v1.z); h[7] = f2bf(v1.w);
        *(u16x8*)&Wf[(size_t)c0 * 8] = h;
    }
}

__global__ __launch_bounds__(512, 1)
void rbf_main2p(const ushort* __restrict__ Xh, const ushort* __restrict__ Xl,
                const ushort* __restrict__ Ch, const ushort* __restrict__ Cl,
                const ushort* __restrict__ Wf, const float* __restrict__ xs2,
                const float2* __restrict__ ecs, float* __restrict__ out, int N)
{
    __shared__ ushort PsA[8][16][PP];
    __shared__ ushort PsB[8][16][PP];
    __shared__ float  Acc[2][32][O + 4];
    __shared__ float  Ls[8][32];

    const int t = threadIdx.x, lane = t & 63, wv = t >> 6;
    const int l15 = lane & 15, l4 = lane >> 4;
    const int pan = blockIdx.x;

    s16x8 xhA[4], xlA[4], xhB[4], xlB[4];
    {
        const size_t baseA = ((size_t)(pan * 2) * 4) * 64 + lane;
        const size_t baseB = ((size_t)(pan * 2 + 1) * 4) * 64 + lane;
#pragma unroll
        for (int q = 0; q < 4; ++q) {
            xhA[q] = *(const s16x8*)&Xh[(baseA + q * 64) * 8];
            xlA[q] = *(const s16x8*)&Xl[(baseA + q * 64) * 8];
            xhB[q] = *(const s16x8*)&Xh[(baseB + q * 64) * 8];
            xlB[q] = *(const s16x8*)&Xl[(baseB + q * 64) * 8];
        }
    }
    const float xs2A = xs2[pan * 32 + l15];
    const float xs2B = xs2[pan * 32 + 16 + l15];

    f32x4 oaccA[16], oaccB[16];
#pragma unroll
    for (int i = 0; i < 16; ++i) {
        oaccA[i] = (f32x4){0.f, 0.f, 0.f, 0.f};
        oaccB[i] = (f32x4){0.f, 0.f, 0.f, 0.f};
    }
    float LpA = 0.f, LpB = 0.f;

    const int kw = wv * 64;

#pragma unroll
    for (int s = 0; s < 2; ++s) {
        const int kslab = (kw >> 5) + s;
        const ushort* wbase = &Wf[(((size_t)kslab * 16) * 64 + lane) * 8];

#pragma unroll
        for (int bt = 0; bt < 2; ++bt) {
            const size_t kt16 = (size_t)(kw >> 4) + s * 2 + bt;
            s16x8 ch[4], cl[4];
#pragma unroll
            for (int q = 0; q < 4; ++q) {
                const size_t cc = ((kt16 * 4 + q) * 64 + lane) * 8;
                ch[q] = *(const s16x8*)&Ch[cc];
                cl[q] = *(const s16x8*)&Cl[cc];
            }
            f32x4 gA = (f32x4){0.f,0.f,0.f,0.f};
            f32x4 gB = (f32x4){0.f,0.f,0.f,0.f};
#pragma unroll
            for (int q = 0; q < 4; ++q) {
                gA = __builtin_amdgcn_mfma_f32_16x16x32_bf16(ch[q], xhA[q], gA, 0, 0, 0);
                gB = __builtin_amdgcn_mfma_f32_16x16x32_bf16(ch[q], xhB[q], gB, 0, 0, 0);
            }
#pragma unroll
            for (int q = 0; q < 4; ++q) {
                gA = __builtin_amdgcn_mfma_f32_16x16x32_bf16(ch[q], xlA[q], gA, 0, 0, 0);
                gB = __builtin_amdgcn_mfma_f32_16x16x32_bf16(ch[q], xlB[q], gB, 0, 0, 0);
            }
#pragma unroll
            for (int q = 0; q < 4; ++q) {
                gA = __builtin_amdgcn_mfma_f32_16x16x32_bf16(cl[q], xhA[q], gA, 0, 0, 0);
                gB = __builtin_amdgcn_mfma_f32_16x16x32_bf16(cl[q], xhB[q], gB, 0, 0, 0);
            }

            const int kbase = kw + s * 32 + bt * 16 + l4 * 4;
            float4 e0 = *(const float4*)&ecs[kbase];
            float4 e1 = *(const float4*)&ecs[kbase + 2];
            {
                float p0 = exp2f(fmaf(e0.x, fmaf(-2.f, gA[0], xs2A), e0.y));
                float p1 = exp2f(fmaf(e0.z, fmaf(-2.f, gA[1], xs2A), e0.w));
                float p2 = exp2f(fmaf(e1.x, fmaf(-2.f, gA[2], xs2A), e1.y));
                float p3 = exp2f(fmaf(e1.z, fmaf(-2.f, gA[3], xs2A), e1.w));
                LpA += (p0 + p1) + (p2 + p3);
                uint u0 = (uint)f2bf(p0) | ((uint)f2bf(p1) << 16);
                uint u1 = (uint)f2bf(p2) | ((uint)f2bf(p3) << 16);
                *(uint2*)&PsA[wv][l15][bt * 16 + l4 * 4] = make_uint2(u0, u1);
            }
            {
                float p0 = exp2f(fmaf(e0.x, fmaf(-2.f, gB[0], xs2B), e0.y));
                float p1 = exp2f(fmaf(e0.z, fmaf(-2.f, gB[1], xs2B), e0.w));
                float p2 = exp2f(fmaf(e1.x, fmaf(-2.f, gB[2], xs2B), e1.y));
                float p3 = exp2f(fmaf(e1.z, fmaf(-2.f, gB[3], xs2B), e1.w));
                LpB += (p0 + p1) + (p2 + p3);
                uint u0 = (uint)f2bf(p0) | ((uint)f2bf(p1) << 16);
                uint u1 = (uint)f2bf(p2) | ((uint)f2bf(p3) << 16);
                *(uint2*)&PsB[wv][l15][bt * 16 + l4 * 4] = make_uint2(u0, u1);
            }
        }

        s16x8 paA = *(const s16x8*)&PsA[wv][l15][l4 * 8];
        s16x8 paB = *(const s16x8*)&PsB[wv][l15][l4 * 8];
#pragma unroll
        for (int ot = 0; ot < 16; ++ot) {
            s16x8 bfr = *(const s16x8*)&wbase[(size_t)ot * 64 * 8];
            oaccA[ot] = __builtin_amdgcn_mfma_f32_16x16x32_bf16(paA, bfr, oaccA[ot], 0, 0, 0);
            oaccB[ot] = __builtin_amdgcn_mfma_f32_16x16x32_bf16(paB, bfr, oaccB[ot], 0, 0, 0);
        }
    }

    {
        float vA = LpA, vB = LpB;
        vA += __shfl_xor(vA, 16);  vA += __shfl_xor(vA, 32);
        vB += __shfl_xor(vB, 16);  vB += __shfl_xor(vB, 32);
        if (lane < 16) {
            Ls[wv][lane]      = vA;
            Ls[wv][16 + lane] = vB;
        }
    }

    if (wv < 2) {
#pragma unroll
        for (int ot = 0; ot < 16; ++ot)
#pragma unroll
            for (int r = 0; r < 4; ++r) {
                Acc[wv][l4 * 4 + r][ot * 16 + l15]      = oaccA[ot][r];
                Acc[wv][16 + l4 * 4 + r][ot * 16 + l15] = oaccB[ot][r];
            }
    }
    __syncthreads();
    if (wv == 2 || wv == 3) {
#pragma unroll
        for (int ot = 0; ot < 16; ++ot)
#pragma unroll
            for (int r = 0; r < 4; ++r) {
                Acc[wv - 2][l4 * 4 + r][ot * 16 + l15]      += oaccA[ot][r];
                Acc[wv - 2][16 + l4 * 4 + r][ot * 16 + l15] += oaccB[ot][r];
            }
    }
    __syncthreads();
    if (wv == 4 || wv == 5) {
#pragma unroll
        for (int ot = 0; ot < 16; ++ot)
#pragma unroll
            for (int r = 0; r < 4; ++r) {
                Acc[wv - 4][l4 * 4 + r][ot * 16 + l15]      += oaccA[ot][r];
                Acc[wv - 4][16 + l4 * 4 + r][ot * 16 + l15] += oaccB[ot][r];
            }
    }
    __syncthreads();
    if (wv >= 6) {
#pragma unroll
        for (int ot = 0; ot < 16; ++ot)
#pragma unroll
            for (int r = 0; r < 4; ++r) {
                Acc[wv - 6][l4 * 4 + r][ot * 16 + l15]      += oaccA[ot][r];
                Acc[wv - 6][16 + l4 * 4 + r][ot * 16 + l15] += oaccB[ot][r];
            }
    }
    __syncthreads();

    {
        const int n  = t >> 4;
        const int c0 = (t & 15) * 16;
        float inv = 1.0f / (Ls[0][n] + Ls[1][n] + Ls[2][n] + Ls[3][n] +
                            Ls[4][n] + Ls[5][n] + Ls[6][n] + Ls[7][n] + 1e-9f);
        float* po = &out[(size_t)(pan * 32 + n) * O + c0];
#pragma unroll
        for (int j = 0; j < 4; ++j) {
            float4 a = *(const float4*)&Acc[0][n][c0 + j * 4];
            float4 b = *(const float4*)&Acc[1][n][c0 + j * 4];
            float4 o;
            o.x = (a.x + b.x) * inv;
            o.y = (a.y + b.y) * inv;
            o.z = (a.z + b.z) * inv;
            o.w = (a.w + b.w) * inv;
            *(float4*)(po + j * 4) = o;
        }
    }
}

// ================= fallback path 2: no-ws single kernel (round-4) =================
__global__ __launch_bounds__(NT, 2)
void rbf_fb(const float* __restrict__ x, const float* __restrict__ cen,
            const float* __restrict__ ls, const float* __restrict__ w,
            float* __restrict__ out)
{
    __shared__ ushort Ps2[2][4][16][PP];
    __shared__ float  Acc2[2][16][O + 4];
    __shared__ float  Ls2[4][16];
    const int t = threadIdx.x, lane = t & 63, wv = t >> 6;
    const int l15 = lane & 15, l4 = lane >> 4;
    const int nb = blockIdx.x * 16;

    s16x8 xh[4], xl[4];
    float sx = 0.f;
    {
        const float* xr = x + (size_t)(nb + l15) * D;
#pragma unroll
        for (int q = 0; q < 4; ++q) {
            float4 v0 = *(const float4*)(xr + q * 32 + l4 * 8);
            float4 v1 = *(const float4*)(xr + q * 32 + l4 * 8 + 4);
            float f[8] = {v0.x, v0.y, v0.z, v0.w, v1.x, v1.y, v1.z, v1.w};
            s16x8 hh, lo;
#pragma unroll
            for (int j = 0; j < 8; ++j) {
                sx = fmaf(f[j], f[j], sx);
                ushort hb = f2bf(f[j]);
                hh[j] = (short)hb; lo[j] = (short)f2bf(f[j] - bf2f(hb));
            }
            xh[q] = hh; xl[q] = lo;
        }
    }
    sx += __shfl_xor(sx, 16); sx += __shfl_xor(sx, 32);
    float xs2v[4];
#pragma unroll
    for (int r = 0; r < 4; ++r) xs2v[r] = __shfl(sx, l4 * 4 + r);

    f32x4 oacc[16];
#pragma unroll
    for (int ot = 0; ot < 16; ++ot) oacc[ot] = (f32x4){0.f,0.f,0.f,0.f};
    float Lp[4] = {0.f,0.f,0.f,0.f};
    const int kq = wv * (K / 4);

#pragma unroll
    for (int s = 0; s < 4; ++s) {
        const int k0 = kq + s * 32;
#pragma unroll
        for (int bt = 0; bt < 2; ++bt) {
            const int kk = k0 + bt * 16 + l15;
            const float* cr = cen + (size_t)kk * D;
            s16x8 ch[4], cl[4];
            float sc = 0.f;
#pragma unroll
            for (int q = 0; q < 4; ++q) {
                float4 v0 = *(const float4*)(cr + q * 32 + l4 * 8);
                float4 v1 = *(const float4*)(cr + q * 32 + l4 * 8 + 4);
                float f[8] = {v0.x, v0.y, v0.z, v0.w, v1.x, v1.y, v1.z, v1.w};
                s16x8 hh, lo;
#pragma unroll
                for (int j = 0; j < 8; ++j) {
                    sc = fmaf(f[j], f[j], sc);
                    ushort hb = f2bf(f[j]);
                    hh[j] = (short)hb; lo[j] = (short)f2bf(f[j] - bf2f(hb));
                }
                ch[q] = hh; cl[q] = lo;
            }
            sc += __shfl_xor(sc, 16); sc += __shfl_xor(sc, 32);
            float es_ = __expf(2.0f * ls[kk]);
            f32x4 ghh={0,0,0,0}, ghl={0,0,0,0}, glh={0,0,0,0};
#pragma unroll
            for (int q = 0; q < 4; ++q) {
                ghh = __builtin_amdgcn_mfma_f32_16x16x32_bf16(xh[q], ch[q], ghh, 0,0,0);
                ghl = __builtin_amdgcn_mfma_f32_16x16x32_bf16(xh[q], cl[q], ghl, 0,0,0);
                glh = __builtin_amdgcn_mfma_f32_16x16x32_bf16(xl[q], ch[q], glh, 0,0,0);
            }
            f32x4 gg = ghh + ghl + glh;
#pragma unroll
            for (int r = 0; r < 4; ++r) {
                float r2 = xs2v[r] + sc - 2.0f * gg[r];
                float ph = __expf(-es_ * r2);
                Lp[r] += ph;
                Ps2[s & 1][wv][l4 * 4 + r][bt * 16 + l15] = f2bf(ph);
            }
        }
        s16x8 pa = *(const s16x8*)&Ps2[s & 1][wv][l15][l4 * 8];
#pragma unroll
        for (int ot = 0; ot < 16; ++ot) {
            const float* wr = w + (size_t)(ot * 16 + l15) * K + k0;
            float4 v0 = *(const float4*)(wr + l4 * 8);
            float4 v1 = *(const float4*)(wr + l4 * 8 + 4);
            s16x8 bb;
            bb[0]=(short)f2bf(v0.x); bb[1]=(short)f2bf(v0.y); bb[2]=(short)f2bf(v0.z); bb[3]=(short)f2bf(v0.w);
            bb[4]=(short)f2bf(v1.x); bb[5]=(short)f2bf(v1.y); bb[6]=(short)f2bf(v1.z); bb[7]=(short)f2bf(v1.w);
            oacc[ot] = __builtin_amdgcn_mfma_f32_16x16x32_bf16(pa, bb, oacc[ot], 0,0,0);
        }
    }
#pragma unroll
    for (int r = 0; r < 4; ++r) {
        float v = Lp[r];
        v += __shfl_xor(v, 1); v += __shfl_xor(v, 2);
        v += __shfl_xor(v, 4); v += __shfl_xor(v, 8);
        if (l15 == 0) Ls2[wv][l4 * 4 + r] = v;
    }
    if (wv < 2) {
#pragma unroll
        for (int ot = 0; ot < 16; ++ot)
#pragma unroll
            for (int r = 0; r < 4; ++r)
                Acc2[wv][l4 * 4 + r][ot * 16 + l15] = oacc[ot][r];
    }
    __syncthreads();
    if (wv >= 2) {
#pragma unroll
        for (int ot = 0; ot < 16; ++ot)
#pragma unroll
            for (int r = 0; r < 4; ++r)
                Acc2[wv - 2][l4 * 4 + r][ot * 16 + l15] += oacc[ot][r];
    }
    __syncthreads();
#pragma unroll
    for (int rr = 0; rr < 4; ++rr) {
        const int n = wv * 4 + rr;
        float inv = 1.0f / (Ls2[0][n] + Ls2[1][n] + Ls2[2][n] + Ls2[3][n] + 1e-9f);
        float4 a0 = *(const float4*)&Acc2[0][n][lane * 4];
        float4 a1 = *(const float4*)&Acc2[1][n][lane * 4];
        float4 o4;
        o4.x = (a0.x + a1.x) * inv; o4.y = (a0.y + a1.y) * inv;
        o4.z = (a0.z + a1.z) * inv; o4.w = (a0.w + a1.w) * inv;
        *(float4*)&out[(size_t)(nb + n) * O + lane * 4] = o4;
    }
}

extern "C" void kernel_launch(void* const* d_in, const int* in_sizes, int n_in,
                              void* d_out, int out_size, void* d_ws, size_t ws_size,
                              hipStream_t stream) {
    const float* x   = (const float*)d_in[0];  // N x 128
    const float* cen = (const float*)d_in[1];  // 512 x 128
    const float* ls  = (const float*)d_in[2];  // 512
    const float* w   = (const float*)d_in[3];  // 256 x 512
    float* out = (float*)d_out;                // N x 256
    const int N = in_sizes[0] / D;             // 8192

    size_t oXh = 0;
    size_t oXl = oXh + (size_t)N * D * 2;
    size_t oCh = oXl + (size_t)N * D * 2;
    size_t oCl = oCh + (size_t)K * D * 2;
    size_t oWf = oCl + (size_t)K * D * 2;
    size_t oxs = oWf + (size_t)O * K * 2;
    size_t oec = oxs + (size_t)N * 4;
    size_t need = oec + (size_t)K * 8;

    if (ws_size < need || N != 8192) {
        dim3 grid(N / 16), block(NT);
        hipLaunchKernelGGL(rbf_fb, grid, block, 0, stream, x, cen, ls, w, out);
        return;
    }

    char* ws = (char*)d_ws;
    ushort* Xh = (ushort*)(ws + oXh);
    ushort* Xl = (ushort*)(ws + oXl);
    ushort* Ch = (ushort*)(ws + oCh);
    ushort* Cl = (ushort*)(ws + oCl);
    ushort* Wf = (ushort*)(ws + oWf);
    float*  xs2 = (float*)(ws + oxs);
    float2* ecs = (float2*)(ws + oec);

    // ---- try single cooperative dispatch ----
    {
        int Nv = N;
        void* params[] = { (void*)&x, (void*)&cen, (void*)&ls, (void*)&w,
                           (void*)&Xh, (void*)&Xl, (void*)&Ch, (void*)&Cl,
                           (void*)&Wf, (void*)&xs2, (void*)&ecs,
                           (void*)&out, (void*)&Nv };
        hipError_t err = hipLaunchCooperativeKernel(
            reinterpret_cast<void*>(&rbf_coop), dim3(N / 32), dim3(512),
            params, 0, stream);
        if (err == hipSuccess) return;
        (void)hipGetLastError();   // clear error state, fall through
    }

    // ---- fallback: round-11 two-kernel pipeline ----
    const int nxb = N / 16;
    const int ncb = K / 16;
    const int nwb = (O * K / 8) / NT;
    dim3 pgrid(nxb + ncb + nwb), pblock(NT);
    hipLaunchKernelGGL(rbf_prep, pgrid, pblock, 0, stream,
                       x, cen, ls, w, Xh, Xl, Ch, Cl, Wf, xs2, ecs, nxb, ncb);

    dim3 grid(N / 32), block(512);
    hipLaunchKernelGGL(rbf_main2p, grid, block, 0, stream,
                       Xh, Xl, Ch, Cl, Wf, xs2, ecs, out, N);
}

// Round 13
// 45.122 us; speedup vs baseline: 1.4684x; 1.4684x over previous
//
#include <hip/hip_runtime.h>

typedef float  f32x4 __attribute__((ext_vector_type(4)));
typedef short  s16x8 __attribute__((ext_vector_type(8)));
typedef ushort u16x8 __attribute__((ext_vector_type(8)));

constexpr int D  = 128;
constexpr int K  = 512;
constexpr int O  = 256;
constexpr int NT = 256;
constexpr float NL2E = -1.44269504088896340736f;  // -log2(e)
constexpr int PP = 40;   // Ps row stride in ushorts

__device__ __forceinline__ ushort f2bf(float f) {
    uint u = __builtin_bit_cast(uint, f);
    return (ushort)((u + 0x7FFFu + ((u >> 16) & 1u)) >> 16);
}
__device__ __forceinline__ float bf2f(ushort h) {
    return __builtin_bit_cast(float, ((uint)h) << 16);
}

// ================= single fused kernel: no workspace, one dispatch =================
// 32 rows/block (2 named panels A/B), 8 waves, wave = K-eighth (64 kernels).
// X hi-frags in regs; X lo-frags in LDS (wave 0 publishes once). C converted
// per-tile inline in frag order; W converted at point of use. GEMM1 swapped
// (A=C, B=X) 3-pass split-bf16; Ps transpose via wave-private LDS (no barrier);
// static 4-stage LDS tree combine. All register arrays static-indexed (rule #20).
__global__ __launch_bounds__(512, 1)
void rbf_fused1(const float* __restrict__ x, const float* __restrict__ cen,
                const float* __restrict__ ls, const float* __restrict__ w,
                float* __restrict__ out)
{
    __shared__ ushort XloL[2][4][64][8];   // 8 KB   [panel][q][lane][8]
    __shared__ ushort PsA[8][16][PP];      // 10.2 KB
    __shared__ ushort PsB[8][16][PP];      // 10.2 KB
    __shared__ float  Acc[2][32][O + 4];   // 66.6 KB
    __shared__ float  Ls[8][32];           // 1 KB    -> total ~96.2 KB

    const int t = threadIdx.x, lane = t & 63, wv = t >> 6;   // wv 0..7
    const int l15 = lane & 15, l4 = lane >> 4;
    const int pan = blockIdx.x;
    const int nb  = pan * 32;

    // ---- X setup: each wave converts its own hi-frags + row norms; wave 0 publishes lo ----
    s16x8 xhA[4], xhB[4];
    float sxA = 0.f, sxB = 0.f;
    {
        const float* xrA = x + (size_t)(nb + l15) * D + l4 * 8;
        const float* xrB = x + (size_t)(nb + 16 + l15) * D + l4 * 8;
#pragma unroll
        for (int q = 0; q < 4; ++q) {
            float4 a0 = *(const float4*)(xrA + q * 32);
            float4 a1 = *(const float4*)(xrA + q * 32 + 4);
            float4 b0 = *(const float4*)(xrB + q * 32);
            float4 b1 = *(const float4*)(xrB + q * 32 + 4);
            float fa[8] = {a0.x,a0.y,a0.z,a0.w,a1.x,a1.y,a1.z,a1.w};
            float fb[8] = {b0.x,b0.y,b0.z,b0.w,b1.x,b1.y,b1.z,b1.w};
            s16x8 ha, hb;
#pragma unroll
            for (int j = 0; j < 8; ++j) {
                sxA = fmaf(fa[j], fa[j], sxA);
                sxB = fmaf(fb[j], fb[j], sxB);
                ha[j] = (short)f2bf(fa[j]);
                hb[j] = (short)f2bf(fb[j]);
            }
            xhA[q] = ha; xhB[q] = hb;
            if (wv == 0) {
                u16x8 la, lb;
#pragma unroll
                for (int j = 0; j < 8; ++j) {
                    la[j] = f2bf(fa[j] - bf2f((ushort)ha[j]));
                    lb[j] = f2bf(fb[j] - bf2f((ushort)hb[j]));
                }
                *(u16x8*)&XloL[0][q][lane][0] = la;
                *(u16x8*)&XloL[1][q][lane][0] = lb;
            }
        }
    }
    sxA += __shfl_xor(sxA, 16);  sxA += __shfl_xor(sxA, 32);
    sxB += __shfl_xor(sxB, 16);  sxB += __shfl_xor(sxB, 32);

    const int kw = wv * 64;  // wave's kernel base
    // per-lane fused coefficient: ne = -log2(e) * exp(2*ls[k]) for k = kw+lane
    const float nev = NL2E * __expf(2.0f * ls[kw + lane]);

    __syncthreads();   // XloL ready

    f32x4 oaccA[16], oaccB[16];
#pragma unroll
    for (int i = 0; i < 16; ++i) {
        oaccA[i] = (f32x4){0.f, 0.f, 0.f, 0.f};
        oaccB[i] = (f32x4){0.f, 0.f, 0.f, 0.f};
    }
    float LpA = 0.f, LpB = 0.f;

#pragma unroll
    for (int s2 = 0; s2 < 2; ++s2) {
        const int kslab = (kw >> 5) + s2;

        // ---- GEMM1 + exp2 for two 16-kernel tiles ----
#pragma unroll
        for (int bt = 0; bt < 2; ++bt) {
            const int tloc = s2 * 2 + bt;               // 0..3 tile within wave
            const int krow = kw + tloc * 16 + l15;      // C row this lane reads
            const float* cr = cen + (size_t)krow * D + l4 * 8;

            s16x8 ch[4], cl[4];
            float sc = 0.f;
#pragma unroll
            for (int q = 0; q < 4; ++q) {
                float4 v0 = *(const float4*)(cr + q * 32);
                float4 v1 = *(const float4*)(cr + q * 32 + 4);
                float f[8] = {v0.x,v0.y,v0.z,v0.w,v1.x,v1.y,v1.z,v1.w};
                s16x8 hh, lo;
#pragma unroll
                for (int j = 0; j < 8; ++j) {
                    sc = fmaf(f[j], f[j], sc);
                    ushort hb = f2bf(f[j]);
                    hh[j] = (short)hb;
                    lo[j] = (short)f2bf(f[j] - bf2f(hb));
                }
                ch[q] = hh; cl[q] = lo;
            }
            sc += __shfl_xor(sc, 16);
            sc += __shfl_xor(sc, 32);    // all lanes: ||c_{krow}||^2 of row l15

            f32x4 gA = (f32x4){0.f,0.f,0.f,0.f};
            f32x4 gB = (f32x4){0.f,0.f,0.f,0.f};
#pragma unroll
            for (int q = 0; q < 4; ++q) {
                gA = __builtin_amdgcn_mfma_f32_16x16x32_bf16(ch[q], xhA[q], gA, 0, 0, 0);
                gB = __builtin_amdgcn_mfma_f32_16x16x32_bf16(ch[q], xhB[q], gB, 0, 0, 0);
            }
#pragma unroll
            for (int q = 0; q < 4; ++q) {
                s16x8 xa = *(const s16x8*)&XloL[0][q][lane][0];
                s16x8 xb = *(const s16x8*)&XloL[1][q][lane][0];
                gA = __builtin_amdgcn_mfma_f32_16x16x32_bf16(ch[q], xa, gA, 0, 0, 0);
                gB = __builtin_amdgcn_mfma_f32_16x16x32_bf16(ch[q], xb, gB, 0, 0, 0);
            }
#pragma unroll
            for (int q = 0; q < 4; ++q) {
                gA = __builtin_amdgcn_mfma_f32_16x16x32_bf16(cl[q], xhA[q], gA, 0, 0, 0);
                gB = __builtin_amdgcn_mfma_f32_16x16x32_bf16(cl[q], xhB[q], gB, 0, 0, 0);
            }

            // lane's 4 output rows = kernels tloc*16 + l4*4 + r, col = data row l15
            const int li0 = tloc * 16 + l4 * 4;
            float ne0 = __shfl(nev, li0 + 0);
            float ne1 = __shfl(nev, li0 + 1);
            float ne2 = __shfl(nev, li0 + 2);
            float ne3 = __shfl(nev, li0 + 3);
            float c20 = __shfl(sc, l4 * 4 + 0);
            float c21 = __shfl(sc, l4 * 4 + 1);
            float c22 = __shfl(sc, l4 * 4 + 2);
            float c23 = __shfl(sc, l4 * 4 + 3);
            {
                float p0 = exp2f(ne0 * fmaf(-2.f, gA[0], sxA + c20));
                float p1 = exp2f(ne1 * fmaf(-2.f, gA[1], sxA + c21));
                float p2 = exp2f(ne2 * fmaf(-2.f, gA[2], sxA + c22));
                float p3 = exp2f(ne3 * fmaf(-2.f, gA[3], sxA + c23));
                LpA += (p0 + p1) + (p2 + p3);
                uint u0 = (uint)f2bf(p0) | ((uint)f2bf(p1) << 16);
                uint u1 = (uint)f2bf(p2) | ((uint)f2bf(p3) << 16);
                *(uint2*)&PsA[wv][l15][bt * 16 + l4 * 4] = make_uint2(u0, u1);
            }
            {
                float p0 = exp2f(ne0 * fmaf(-2.f, gB[0], sxB + c20));
                float p1 = exp2f(ne1 * fmaf(-2.f, gB[1], sxB + c21));
                float p2 = exp2f(ne2 * fmaf(-2.f, gB[2], sxB + c22));
                float p3 = exp2f(ne3 * fmaf(-2.f, gB[3], sxB + c23));
                LpB += (p0 + p1) + (p2 + p3);
                uint u0 = (uint)f2bf(p0) | ((uint)f2bf(p1) << 16);
                uint u1 = (uint)f2bf(p2) | ((uint)f2bf(p3) << 16);
                *(uint2*)&PsB[wv][l15][bt * 16 + l4 * 4] = make_uint2(u0, u1);
            }
        }

        // ---- wave-private transpose read (same-wave DS order) + GEMM2 ----
        s16x8 paA = *(const s16x8*)&PsA[wv][l15][l4 * 8];
        s16x8 paB = *(const s16x8*)&PsB[wv][l15][l4 * 8];
#pragma unroll
        for (int ot = 0; ot < 16; ++ot) {
            const float* wr = w + (size_t)(ot * 16 + l15) * K + kslab * 32 + l4 * 8;
            float4 v0 = *(const float4*)wr;
            float4 v1 = *(const float4*)(wr + 4);
            s16x8 bb;
            bb[0]=(short)f2bf(v0.x); bb[1]=(short)f2bf(v0.y);
            bb[2]=(short)f2bf(v0.z); bb[3]=(short)f2bf(v0.w);
            bb[4]=(short)f2bf(v1.x); bb[5]=(short)f2bf(v1.y);
            bb[6]=(short)f2bf(v1.z); bb[7]=(short)f2bf(v1.w);
            oaccA[ot] = __builtin_amdgcn_mfma_f32_16x16x32_bf16(paA, bb, oaccA[ot], 0, 0, 0);
            oaccB[ot] = __builtin_amdgcn_mfma_f32_16x16x32_bf16(paB, bb, oaccB[ot], 0, 0, 0);
        }
    }

    // ---- per-wave row sums over its 64 kernels ----
    {
        float vA = LpA, vB = LpB;
        vA += __shfl_xor(vA, 16);  vA += __shfl_xor(vA, 32);
        vB += __shfl_xor(vB, 16);  vB += __shfl_xor(vB, 32);
        if (lane < 16) {
            Ls[wv][lane]      = vA;
            Ls[wv][16 + lane] = vB;
        }
    }

    // ---- combine 8 wave partials into 2 buffers: static 4-stage tree ----
    if (wv < 2) {
#pragma unroll
        for (int ot = 0; ot < 16; ++ot)
#pragma unroll
            for (int r = 0; r < 4; ++r) {
                Acc[wv][l4 * 4 + r][ot * 16 + l15]      = oaccA[ot][r];
                Acc[wv][16 + l4 * 4 + r][ot * 16 + l15] = oaccB[ot][r];
            }
    }
    __syncthreads();
    if (wv == 2 || wv == 3) {
#pragma unroll
        for (int ot = 0; ot < 16; ++ot)
#pragma unroll
            for (int r = 0; r < 4; ++r) {
                Acc[wv - 2][l4 * 4 + r][ot * 16 + l15]      += oaccA[ot][r];
                Acc[wv - 2][16 + l4 * 4 + r][ot * 16 + l15] += oaccB[ot][r];
            }
    }
    __syncthreads();
    if (wv == 4 || wv == 5) {
#pragma unroll
        for (int ot = 0; ot < 16; ++ot)
#pragma unroll
            for (int r = 0; r < 4; ++r) {
                Acc[wv - 4][l4 * 4 + r][ot * 16 + l15]      += oaccA[ot][r];
                Acc[wv - 4][16 + l4 * 4 + r][ot * 16 + l15] += oaccB[ot][r];
            }
    }
    __syncthreads();
    if (wv >= 6) {
#pragma unroll
        for (int ot = 0; ot < 16; ++ot)
#pragma unroll
            for (int r = 0; r < 4; ++r) {
                Acc[wv - 6][l4 * 4 + r][ot * 16 + l15]      += oaccA[ot][r];
                Acc[wv - 6][16 + l4 * 4 + r][ot * 16 + l15] += oaccB[ot][r];
            }
    }
    __syncthreads();

    // ---- store: sum 2 buffers + normalize ----
    {
        const int n  = t >> 4;           // 0..31
        const int c0 = (t & 15) * 16;    // 0..240
        float inv = 1.0f / (Ls[0][n] + Ls[1][n] + Ls[2][n] + Ls[3][n] +
                            Ls[4][n] + Ls[5][n] + Ls[6][n] + Ls[7][n] + 1e-9f);
        float* po = &out[(size_t)(nb + n) * O + c0];
#pragma unroll
        for (int j = 0; j < 4; ++j) {
            float4 a = *(const float4*)&Acc[0][n][c0 + j * 4];
            float4 b = *(const float4*)&Acc[1][n][c0 + j * 4];
            float4 o;
            o.x = (a.x + b.x) * inv;
            o.y = (a.y + b.y) * inv;
            o.z = (a.z + b.z) * inv;
            o.w = (a.w + b.w) * inv;
            *(float4*)(po + j * 4) = o;
        }
    }
}

// ================= fallback for N % 32 != 0 (round-4 kernel, known-pass) =================
__global__ __launch_bounds__(NT, 2)
void rbf_fb(const float* __restrict__ x, const float* __restrict__ cen,
            const float* __restrict__ ls, const float* __restrict__ w,
            float* __restrict__ out)
{
    __shared__ ushort Ps2[2][4][16][PP];
    __shared__ float  Acc2[2][16][O + 4];
    __shared__ float  Ls2[4][16];
    const int t = threadIdx.x, lane = t & 63, wv = t >> 6;
    const int l15 = lane & 15, l4 = lane >> 4;
    const int nb = blockIdx.x * 16;

    s16x8 xh[4], xl[4];
    float sx = 0.f;
    {
        const float* xr = x + (size_t)(nb + l15) * D;
#pragma unroll
        for (int q = 0; q < 4; ++q) {
            float4 v0 = *(const float4*)(xr + q * 32 + l4 * 8);
            float4 v1 = *(const float4*)(xr + q * 32 + l4 * 8 + 4);
            float f[8] = {v0.x, v0.y, v0.z, v0.w, v1.x, v1.y, v1.z, v1.w};
            s16x8 hh, lo;
#pragma unroll
            for (int j = 0; j < 8; ++j) {
                sx = fmaf(f[j], f[j], sx);
                ushort hb = f2bf(f[j]);
                hh[j] = (short)hb; lo[j] = (short)f2bf(f[j] - bf2f(hb));
            }
            xh[q] = hh; xl[q] = lo;
        }
    }
    sx += __shfl_xor(sx, 16); sx += __shfl_xor(sx, 32);
    float xs2v[4];
#pragma unroll
    for (int r = 0; r < 4; ++r) xs2v[r] = __shfl(sx, l4 * 4 + r);

    f32x4 oacc[16];
#pragma unroll
    for (int ot = 0; ot < 16; ++ot) oacc[ot] = (f32x4){0.f,0.f,0.f,0.f};
    float Lp[4] = {0.f,0.f,0.f,0.f};
    const int kq = wv * (K / 4);

#pragma unroll
    for (int s = 0; s < 4; ++s) {
        const int k0 = kq + s * 32;
#pragma unroll
        for (int bt = 0; bt < 2; ++bt) {
            const int kk = k0 + bt * 16 + l15;
            const float* cr = cen + (size_t)kk * D;
            s16x8 ch[4], cl[4];
            float sc = 0.f;
#pragma unroll
            for (int q = 0; q < 4; ++q) {
                float4 v0 = *(const float4*)(cr + q * 32 + l4 * 8);
                float4 v1 = *(const float4*)(cr + q * 32 + l4 * 8 + 4);
                float f[8] = {v0.x, v0.y, v0.z, v0.w, v1.x, v1.y, v1.z, v1.w};
                s16x8 hh, lo;
#pragma unroll
                for (int j = 0; j < 8; ++j) {
                    sc = fmaf(f[j], f[j], sc);
                    ushort hb = f2bf(f[j]);
                    hh[j] = (short)hb; lo[j] = (short)f2bf(f[j] - bf2f(hb));
                }
                ch[q] = hh; cl[q] = lo;
            }
            sc += __shfl_xor(sc, 16); sc += __shfl_xor(sc, 32);
            float es_ = __expf(2.0f * ls[kk]);
            f32x4 ghh={0,0,0,0}, ghl={0,0,0,0}, glh={0,0,0,0};
#pragma unroll
            for (int q = 0; q < 4; ++q) {
                ghh = __builtin_amdgcn_mfma_f32_16x16x32_bf16(xh[q], ch[q], ghh, 0,0,0);
                ghl = __builtin_amdgcn_mfma_f32_16x16x32_bf16(xh[q], cl[q], ghl, 0,0,0);
                glh = __builtin_amdgcn_mfma_f32_16x16x32_bf16(xl[q], ch[q], glh, 0,0,0);
            }
            f32x4 gg = ghh + ghl + glh;
#pragma unroll
            for (int r = 0; r < 4; ++r) {
                float r2 = xs2v[r] + sc - 2.0f * gg[r];
                float ph = __expf(-es_ * r2);
                Lp[r] += ph;
                Ps2[s & 1][wv][l4 * 4 + r][bt * 16 + l15] = f2bf(ph);
            }
        }
        s16x8 pa = *(const s16x8*)&Ps2[s & 1][wv][l15][l4 * 8];
#pragma unroll
        for (int ot = 0; ot < 16; ++ot) {
            const float* wr = w + (size_t)(ot * 16 + l15) * K + k0;
            float4 v0 = *(const float4*)(wr + l4 * 8);
            float4 v1 = *(const float4*)(wr + l4 * 8 + 4);
            s16x8 bb;
            bb[0]=(short)f2bf(v0.x); bb[1]=(short)f2bf(v0.y); bb[2]=(short)f2bf(v0.z); bb[3]=(short)f2bf(v0.w);
            bb[4]=(short)f2bf(v1.x); bb[5]=(short)f2bf(v1.y); bb[6]=(short)f2bf(v1.z); bb[7]=(short)f2bf(v1.w);
            oacc[ot] = __builtin_amdgcn_mfma_f32_16x16x32_bf16(pa, bb, oacc[ot], 0,0,0);
        }
    }
#pragma unroll
    for (int r = 0; r < 4; ++r) {
        float v = Lp[r];
        v += __shfl_xor(v, 1); v += __shfl_xor(v, 2);
        v += __shfl_xor(v, 4); v += __shfl_xor(v, 8);
        if (l15 == 0) Ls2[wv][l4 * 4 + r] = v;
    }
    if (wv < 2) {
#pragma unroll
        for (int ot = 0; ot < 16; ++ot)
#pragma unroll
            for (int r = 0; r < 4; ++r)
                Acc2[wv][l4 * 4 + r][ot * 16 + l15] = oacc[ot][r];
    }
    __syncthreads();
    if (wv >= 2) {
#pragma unroll
        for (int ot = 0; ot < 16; ++ot)
#pragma unroll
            for (int r = 0; r < 4; ++r)
                Acc2[wv - 2][l4 * 4 + r][ot * 16 + l15] += oacc[ot][r];
    }
    __syncthreads();
#pragma unroll
    for (int rr = 0; rr < 4; ++rr) {
        const int n = wv * 4 + rr;
        float inv = 1.0f / (Ls2[0][n] + Ls2[1][n] + Ls2[2][n] + Ls2[3][n] + 1e-9f);
        float4 a0 = *(const float4*)&Acc2[0][n][lane * 4];
        float4 a1 = *(const float4*)&Acc2[1][n][lane * 4];
        float4 o4;
        o4.x = (a0.x + a1.x) * inv; o4.y = (a0.y + a1.y) * inv;
        o4.z = (a0.z + a1.z) * inv; o4.w = (a0.w + a1.w) * inv;
        *(float4*)&out[(size_t)(nb + n) * O + lane * 4] = o4;
    }
}

extern "C" void kernel_launch(void* const* d_in, const int* in_sizes, int n_in,
                              void* d_out, int out_size, void* d_ws, size_t ws_size,
                              hipStream_t stream) {
    const float* x   = (const float*)d_in[0];  // N x 128
    const float* cen = (const float*)d_in[1];  // 512 x 128
    const float* ls  = (const float*)d_in[2];  // 512
    const float* w   = (const float*)d_in[3];  // 256 x 512
    float* out = (float*)d_out;                // N x 256
    const int N = in_sizes[0] / D;             // 8192

    if ((N % 32) != 0) {
        dim3 grid(N / 16), block(NT);
        hipLaunchKernelGGL(rbf_fb, grid, block, 0, stream, x, cen, ls, w, out);
        return;
    }

    dim3 grid(N / 32), block(512);
    hipLaunchKernelGGL(rbf_fused1, grid, block, 0, stream, x, cen, ls, w, out);
}

// Round 14
// 30.026 us; speedup vs baseline: 2.2066x; 1.5028x over previous
//
#include <hip/hip_runtime.h>

typedef float  f32x4 __attribute__((ext_vector_type(4)));
typedef short  s16x8 __attribute__((ext_vector_type(8)));
typedef ushort u16x8 __attribute__((ext_vector_type(8)));

constexpr int D  = 128;
constexpr int K  = 512;
constexpr int O  = 256;
constexpr int NT = 256;
constexpr float NL2E = -1.44269504088896340736f;  // -log2(e)
constexpr int PP = 40;   // Ps row stride in ushorts

__device__ __forceinline__ ushort f2bf(float f) {
    uint u = __builtin_bit_cast(uint, f);
    return (ushort)((u + 0x7FFFu + ((u >> 16) & 1u)) >> 16);
}
__device__ __forceinline__ float bf2f(ushort h) {
    return __builtin_bit_cast(float, ((uint)h) << 16);
}

// ================= prep (C + W ONLY — X is converted inline in main) =================
// frag layout: chunk c = 64 lanes x 8 bf16, 16B/lane contiguous.
// C: c = (panel16*4 + q)*64 + lane ; elem = cen[panel*16 + (lane&15)][q*32 + (lane>>4)*8 + j]
// W: c = (kslab32*16 + ot)*64 + lane; elem = w[ot*16 + (lane&15)][kslab*32 + (lane>>4)*8 + j]
__global__ __launch_bounds__(NT)
void rbf_prepcw(const float* __restrict__ cen, const float* __restrict__ ls,
                const float* __restrict__ w,
                ushort* __restrict__ Ch, ushort* __restrict__ Cl,
                ushort* __restrict__ Wf, float2* __restrict__ ecs)
{
    __shared__ float red[4][16];
    const int b = blockIdx.x, t = threadIdx.x, lane = t & 63, wq = t >> 6;

    if (b < 32) {                      // ---- C panels ----
        const int panel = b;
        const int row = panel * 16 + (lane & 15);
        const int col = wq * 32 + (lane >> 4) * 8;
        const float* p = cen + (size_t)row * D + col;
        float4 v0 = *(const float4*)p, v1 = *(const float4*)(p + 4);
        float f[8] = {v0.x, v0.y, v0.z, v0.w, v1.x, v1.y, v1.z, v1.w};
        u16x8 h, l;
        float s = 0.f;
#pragma unroll
        for (int j = 0; j < 8; ++j) {
            s = fmaf(f[j], f[j], s);
            ushort hb = f2bf(f[j]);
            h[j] = hb;
            l[j] = f2bf(f[j] - bf2f(hb));
        }
        const size_t c = ((size_t)panel * 4 + wq) * 64 + lane;
        *(u16x8*)&Ch[c * 8] = h;
        *(u16x8*)&Cl[c * 8] = l;
        s += __shfl_xor(s, 16);
        s += __shfl_xor(s, 32);
        if (lane < 16) red[wq][lane] = s;
        __syncthreads();
        if (t < 16) {
            float sum = red[0][t] + red[1][t] + red[2][t] + red[3][t];
            int k = panel * 16 + t;
            float e = __expf(2.0f * ls[k]);
            ecs[k] = make_float2(NL2E * e, NL2E * e * sum);
        }
    } else {                           // ---- W blocks ----
        const int c0 = (b - 32) * NT + t;
        const int ln = c0 & 63, ot = (c0 >> 6) & 15, ks = c0 >> 10;
        const int o  = ot * 16 + (ln & 15);
        const int kb = ks * 32 + (ln >> 4) * 8;
        const float* p = w + (size_t)o * K + kb;
        float4 v0 = *(const float4*)p, v1 = *(const float4*)(p + 4);
        u16x8 h;
        h[0] = f2bf(v0.x); h[1] = f2bf(v0.y); h[2] = f2bf(v0.z); h[3] = f2bf(v0.w);
        h[4] = f2bf(v1.x); h[5] = f2bf(v1.y); h[6] = f2bf(v1.z); h[7] = f2bf(v1.w);
        *(u16x8*)&Wf[(size_t)c0 * 8] = h;
    }
}

// ================= main: R10 main8 with inline X conversion =================
// 16 rows/block, 8 waves (512 thr), wave = K-eighth (64 kernels).
// X converted inline per wave (block-private); C/W read bf16 frag-ordered from ws.
// All oacc indices compile-time (rule #20). Static 2-stage LDS tree combine.
__global__ __launch_bounds__(512, 2)   // 2 blocks/CU: 16 waves/CU, VGPR cap 128
void rbf_main8x(const float* __restrict__ x,
                const ushort* __restrict__ Ch, const ushort* __restrict__ Cl,
                const ushort* __restrict__ Wf, const float2* __restrict__ ecs,
                float* __restrict__ out)
{
    __shared__ ushort Ps[8][16][PP];      // 10.2 KB
    __shared__ float  Acc[4][16][O + 4];  // 66.6 KB
    __shared__ float  Ls[8][32];          // 1 KB

    const int t = threadIdx.x, lane = t & 63, wv = t >> 6;   // wv 0..7
    const int l15 = lane & 15, l4 = lane >> 4;
    const int pan = blockIdx.x;
    const int nb  = pan * 16;

    // ---- X fragments: inline fp32 -> bf16 hi/lo + row norm (per-wave, block-private) ----
    s16x8 xh[4], xl[4];
    float sx = 0.f;
    {
        const float* xr = x + (size_t)(nb + l15) * D + l4 * 8;
#pragma unroll
        for (int q = 0; q < 4; ++q) {
            float4 v0 = *(const float4*)(xr + q * 32);
            float4 v1 = *(const float4*)(xr + q * 32 + 4);
            float f[8] = {v0.x, v0.y, v0.z, v0.w, v1.x, v1.y, v1.z, v1.w};
            s16x8 hh, lo;
#pragma unroll
            for (int j = 0; j < 8; ++j) {
                sx = fmaf(f[j], f[j], sx);
                ushort hb = f2bf(f[j]);
                hh[j] = (short)hb;
                lo[j] = (short)f2bf(f[j] - bf2f(hb));
            }
            xh[q] = hh; xl[q] = lo;
        }
    }
    sx += __shfl_xor(sx, 16);
    sx += __shfl_xor(sx, 32);
    const float xs2v = sx;      // ||x_{nb+l15}||^2

    f32x4 oacc[16];
#pragma unroll
    for (int i = 0; i < 16; ++i) oacc[i] = (f32x4){0.f, 0.f, 0.f, 0.f};
    float Lp = 0.f;

    const int kw = wv * 64;   // wave's kernel base (K-eighth)

#pragma unroll
    for (int s = 0; s < 2; ++s) {
        const int kslab = (kw >> 5) + s;
        const ushort* wbase = &Wf[(((size_t)kslab * 16) * 64 + lane) * 8];

        // GEMM1 (swapped: A=C, B=X) + exp2, two 16-kernel tiles
#pragma unroll
        for (int bt = 0; bt < 2; ++bt) {
            const size_t kt16 = (size_t)(kw >> 4) + s * 2 + bt;
            s16x8 ch[4], cl[4];
#pragma unroll
            for (int q = 0; q < 4; ++q) {
                const size_t cc = ((kt16 * 4 + q) * 64 + lane) * 8;
                ch[q] = *(const s16x8*)&Ch[cc];
                cl[q] = *(const s16x8*)&Cl[cc];
            }
            f32x4 ghh = (f32x4){0.f,0.f,0.f,0.f};
            f32x4 ghl = (f32x4){0.f,0.f,0.f,0.f};
            f32x4 glh = (f32x4){0.f,0.f,0.f,0.f};
#pragma unroll
            for (int q = 0; q < 4; ++q) {
                ghh = __builtin_amdgcn_mfma_f32_16x16x32_bf16(ch[q], xh[q], ghh, 0, 0, 0);
                ghl = __builtin_amdgcn_mfma_f32_16x16x32_bf16(ch[q], xl[q], ghl, 0, 0, 0);
                glh = __builtin_amdgcn_mfma_f32_16x16x32_bf16(cl[q], xh[q], glh, 0, 0, 0);
            }
            f32x4 g = ghh + ghl + glh;

            const int kbase = kw + s * 32 + bt * 16 + l4 * 4;
            float4 e0 = *(const float4*)&ecs[kbase];
            float4 e1 = *(const float4*)&ecs[kbase + 2];
            float ph0 = exp2f(fmaf(e0.x, fmaf(-2.f, g[0], xs2v), e0.y));
            float ph1 = exp2f(fmaf(e0.z, fmaf(-2.f, g[1], xs2v), e0.w));
            float ph2 = exp2f(fmaf(e1.x, fmaf(-2.f, g[2], xs2v), e1.y));
            float ph3 = exp2f(fmaf(e1.z, fmaf(-2.f, g[3], xs2v), e1.w));
            Lp += (ph0 + ph1) + (ph2 + ph3);
            uint p0 = (uint)f2bf(ph0) | ((uint)f2bf(ph1) << 16);
            uint p1 = (uint)f2bf(ph2) | ((uint)f2bf(ph3) << 16);
            *(uint2*)&Ps[wv][l15][bt * 16 + l4 * 4] = make_uint2(p0, p1);
        }

        // wave-private transpose read (same-wave DS order, no barrier) + GEMM2
        s16x8 pa = *(const s16x8*)&Ps[wv][l15][l4 * 8];
#pragma unroll
        for (int ot = 0; ot < 16; ++ot) {
            s16x8 bfr = *(const s16x8*)&wbase[(size_t)ot * 64 * 8];
            oacc[ot] = __builtin_amdgcn_mfma_f32_16x16x32_bf16(pa, bfr, oacc[ot], 0, 0, 0);
        }
    }

    // per-wave row sums (over its 64 kernels)
    {
        float v = Lp;
        v += __shfl_xor(v, 16);
        v += __shfl_xor(v, 32);
        if (lane < 16) Ls[wv][lane] = v;
    }

    // ---- combine 8 wave partials: static 2-stage tree ----
    if (wv < 4) {
#pragma unroll
        for (int ot = 0; ot < 16; ++ot)
#pragma unroll
            for (int r = 0; r < 4; ++r)
                Acc[wv][l4 * 4 + r][ot * 16 + l15] = oacc[ot][r];
    }
    __syncthreads();
    if (wv >= 4) {
#pragma unroll
        for (int ot = 0; ot < 16; ++ot)
#pragma unroll
            for (int r = 0; r < 4; ++r)
                Acc[wv - 4][l4 * 4 + r][ot * 16 + l15] += oacc[ot][r];
    }
    __syncthreads();

    // ---- store: sum 4 buffers + normalize; 512 thr, each 8 floats of one row ----
    {
        const int n  = t >> 5;          // 0..15
        const int c8 = (t & 31) * 8;
        float inv = 1.0f / (Ls[0][n] + Ls[1][n] + Ls[2][n] + Ls[3][n] +
                            Ls[4][n] + Ls[5][n] + Ls[6][n] + Ls[7][n] + 1e-9f);
        float4 a0 = *(const float4*)&Acc[0][n][c8];
        float4 b0 = *(const float4*)&Acc[1][n][c8];
        float4 c0 = *(const float4*)&Acc[2][n][c8];
        float4 d0 = *(const float4*)&Acc[3][n][c8];
        float4 a1 = *(const float4*)&Acc[0][n][c8 + 4];
        float4 b1 = *(const float4*)&Acc[1][n][c8 + 4];
        float4 c1 = *(const float4*)&Acc[2][n][c8 + 4];
        float4 d1 = *(const float4*)&Acc[3][n][c8 + 4];
        float4 o0, o1;
        o0.x = ((a0.x + b0.x) + (c0.x + d0.x)) * inv;
        o0.y = ((a0.y + b0.y) + (c0.y + d0.y)) * inv;
        o0.z = ((a0.z + b0.z) + (c0.z + d0.z)) * inv;
        o0.w = ((a0.w + b0.w) + (c0.w + d0.w)) * inv;
        o1.x = ((a1.x + b1.x) + (c1.x + d1.x)) * inv;
        o1.y = ((a1.y + b1.y) + (c1.y + d1.y)) * inv;
        o1.z = ((a1.z + b1.z) + (c1.z + d1.z)) * inv;
        o1.w = ((a1.w + b1.w) + (c1.w + d1.w)) * inv;
        float* po = &out[(size_t)(nb + n) * O + c8];
        *(float4*)po = o0;
        *(float4*)(po + 4) = o1;
    }
}

// ================= fallback (round-4 kernel, known-pass, no ws) =================
__global__ __launch_bounds__(NT, 2)
void rbf_fb(const float* __restrict__ x, const float* __restrict__ cen,
            const float* __restrict__ ls, const float* __restrict__ w,
            float* __restrict__ out)
{
    __shared__ ushort Ps2[2][4][16][PP];
    __shared__ float  Acc2[2][16][O + 4];
    __shared__ float  Ls2[4][16];
    const int t = threadIdx.x, lane = t & 63, wv = t >> 6;
    const int l15 = lane & 15, l4 = lane >> 4;
    const int nb = blockIdx.x * 16;

    s16x8 xh[4], xl[4];
    float sx = 0.f;
    {
        const float* xr = x + (size_t)(nb + l15) * D;
#pragma unroll
        for (int q = 0; q < 4; ++q) {
            float4 v0 = *(const float4*)(xr + q * 32 + l4 * 8);
            float4 v1 = *(const float4*)(xr + q * 32 + l4 * 8 + 4);
            float f[8] = {v0.x, v0.y, v0.z, v0.w, v1.x, v1.y, v1.z, v1.w};
            s16x8 hh, lo;
#pragma unroll
            for (int j = 0; j < 8; ++j) {
                sx = fmaf(f[j], f[j], sx);
                ushort hb = f2bf(f[j]);
                hh[j] = (short)hb; lo[j] = (short)f2bf(f[j] - bf2f(hb));
            }
            xh[q] = hh; xl[q] = lo;
        }
    }
    sx += __shfl_xor(sx, 16); sx += __shfl_xor(sx, 32);
    float xs2v[4];
#pragma unroll
    for (int r = 0; r < 4; ++r) xs2v[r] = __shfl(sx, l4 * 4 + r);

    f32x4 oacc[16];
#pragma unroll
    for (int ot = 0; ot < 16; ++ot) oacc[ot] = (f32x4){0.f,0.f,0.f,0.f};
    float Lp[4] = {0.f,0.f,0.f,0.f};
    const int kq = wv * (K / 4);

#pragma unroll
    for (int s = 0; s < 4; ++s) {
        const int k0 = kq + s * 32;
#pragma unroll
        for (int bt = 0; bt < 2; ++bt) {
            const int kk = k0 + bt * 16 + l15;
            const float* cr = cen + (size_t)kk * D;
            s16x8 ch[4], cl[4];
            float sc = 0.f;
#pragma unroll
            for (int q = 0; q < 4; ++q) {
                float4 v0 = *(const float4*)(cr + q * 32 + l4 * 8);
                float4 v1 = *(const float4*)(cr + q * 32 + l4 * 8 + 4);
                float f[8] = {v0.x, v0.y, v0.z, v0.w, v1.x, v1.y, v1.z, v1.w};
                s16x8 hh, lo;
#pragma unroll
                for (int j = 0; j < 8; ++j) {
                    sc = fmaf(f[j], f[j], sc);
                    ushort hb = f2bf(f[j]);
                    hh[j] = (short)hb; lo[j] = (short)f2bf(f[j] - bf2f(hb));
                }
                ch[q] = hh; cl[q] = lo;
            }
            sc += __shfl_xor(sc, 16); sc += __shfl_xor(sc, 32);
            float es_ = __expf(2.0f * ls[kk]);
            f32x4 ghh={0,0,0,0}, ghl={0,0,0,0}, glh={0,0,0,0};
#pragma unroll
            for (int q = 0; q < 4; ++q) {
                ghh = __builtin_amdgcn_mfma_f32_16x16x32_bf16(xh[q], ch[q], ghh, 0,0,0);
                ghl = __builtin_amdgcn_mfma_f32_16x16x32_bf16(xh[q], cl[q], ghl, 0,0,0);
                glh = __builtin_amdgcn_mfma_f32_16x16x32_bf16(xl[q], ch[q], glh, 0,0,0);
            }
            f32x4 gg = ghh + ghl + glh;
#pragma unroll
            for (int r = 0; r < 4; ++r) {
                float r2 = xs2v[r] + sc - 2.0f * gg[r];
                float ph = __expf(-es_ * r2);
                Lp[r] += ph;
                Ps2[s & 1][wv][l4 * 4 + r][bt * 16 + l15] = f2bf(ph);
            }
        }
        s16x8 pa = *(const s16x8*)&Ps2[s & 1][wv][l15][l4 * 8];
#pragma unroll
        for (int ot = 0; ot < 16; ++ot) {
            const float* wr = w + (size_t)(ot * 16 + l15) * K + k0;
            float4 v0 = *(const float4*)(wr + l4 * 8);
            float4 v1 = *(const float4*)(wr + l4 * 8 + 4);
            s16x8 bb;
            bb[0]=(short)f2bf(v0.x); bb[1]=(short)f2bf(v0.y); bb[2]=(short)f2bf(v0.z); bb[3]=(short)f2bf(v0.w);
            bb[4]=(short)f2bf(v1.x); bb[5]=(short)f2bf(v1.y); bb[6]=(short)f2bf(v1.z); bb[7]=(short)f2bf(v1.w);
            oacc[ot] = __builtin_amdgcn_mfma_f32_16x16x32_bf16(pa, bb, oacc[ot], 0,0,0);
        }
    }
#pragma unroll
    for (int r = 0; r < 4; ++r) {
        float v = Lp[r];
        v += __shfl_xor(v, 1); v += __shfl_xor(v, 2);
        v += __shfl_xor(v, 4); v += __shfl_xor(v, 8);
        if (l15 == 0) Ls2[wv][l4 * 4 + r] = v;
    }
    if (wv < 2) {
#pragma unroll
        for (int ot = 0; ot < 16; ++ot)
#pragma unroll
            for (int r = 0; r < 4; ++r)
                Acc2[wv][l4 * 4 + r][ot * 16 + l15] = oacc[ot][r];
    }
    __syncthreads();
    if (wv >= 2) {
#pragma unroll
        for (int ot = 0; ot < 16; ++ot)
#pragma unroll
            for (int r = 0; r < 4; ++r)
                Acc2[wv - 2][l4 * 4 + r][ot * 16 + l15] += oacc[ot][r];
    }
    __syncthreads();
#pragma unroll
    for (int rr = 0; rr < 4; ++rr) {
        const int n = wv * 4 + rr;
        float inv = 1.0f / (Ls2[0][n] + Ls2[1][n] + Ls2[2][n] + Ls2[3][n] + 1e-9f);
        float4 a0 = *(const float4*)&Acc2[0][n][lane * 4];
        float4 a1 = *(const float4*)&Acc2[1][n][lane * 4];
        float4 o4;
        o4.x = (a0.x + a1.x) * inv; o4.y = (a0.y + a1.y) * inv;
        o4.z = (a0.z + a1.z) * inv; o4.w = (a0.w + a1.w) * inv;
        *(float4*)&out[(size_t)(nb + n) * O + lane * 4] = o4;
    }
}

extern "C" void kernel_launch(void* const* d_in, const int* in_sizes, int n_in,
                              void* d_out, int out_size, void* d_ws, size_t ws_size,
                              hipStream_t stream) {
    const float* x   = (const float*)d_in[0];  // N x 128
    const float* cen = (const float*)d_in[1];  // 512 x 128
    const float* ls  = (const float*)d_in[2];  // 512
    const float* w   = (const float*)d_in[3];  // 256 x 512
    float* out = (float*)d_out;                // N x 256
    const int N = in_sizes[0] / D;             // 8192

    size_t oCh = 0;
    size_t oCl = oCh + (size_t)K * D * 2;
    size_t oWf = oCl + (size_t)K * D * 2;
    size_t oec = oWf + (size_t)O * K * 2;
    size_t need = oec + (size_t)K * 8;

    if (ws_size < need || (N % 16) != 0) {
        dim3 grid(N / 16), block(NT);
        hipLaunchKernelGGL(rbf_fb, grid, block, 0, stream, x, cen, ls, w, out);
        return;
    }

    char* ws = (char*)d_ws;
    ushort* Ch = (ushort*)(ws + oCh);
    ushort* Cl = (ushort*)(ws + oCl);
    ushort* Wf = (ushort*)(ws + oWf);
    float2* ecs = (float2*)(ws + oec);

    // prep: 32 C panels + 64 W blocks = 96 blocks (X handled inline in main)
    dim3 pgrid(32 + (O * K / 8) / NT), pblock(NT);
    hipLaunchKernelGGL(rbf_prepcw, pgrid, pblock, 0, stream,
                       cen, ls, w, Ch, Cl, Wf, ecs);

    dim3 grid(N / 16), block(512);
    hipLaunchKernelGGL(rbf_main8x, grid, block, 0, stream,
                       x, Ch, Cl, Wf, ecs, out);
}

// Round 15
// 28.849 us; speedup vs baseline: 2.2966x; 1.0408x over previous
//
#include <hip/hip_runtime.h>

typedef float  f32x4 __attribute__((ext_vector_type(4)));
typedef short  s16x8 __attribute__((ext_vector_type(8)));
typedef ushort u16x8 __attribute__((ext_vector_type(8)));

constexpr int D  = 128;
constexpr int K  = 512;
constexpr int O  = 256;
constexpr int NT = 256;
constexpr float NL2E = -1.44269504088896340736f;  // -log2(e)
constexpr int PP = 40;   // Ps row stride in ushorts

__device__ __forceinline__ ushort f2bf(float f) {
    uint u = __builtin_bit_cast(uint, f);
    return (ushort)((u + 0x7FFFu + ((u >> 16) & 1u)) >> 16);
}
__device__ __forceinline__ float bf2f(ushort h) {
    return __builtin_bit_cast(float, ((uint)h) << 16);
}

// ================= prep (C + W only; X handled in-block in main) =================
// frag layout: chunk c = 64 lanes x 8 bf16, 16B/lane contiguous.
// C: c = (panel16*4 + q)*64 + lane ; elem = cen[panel*16 + (lane&15)][q*32 + (lane>>4)*8 + j]
// W: c = (kslab32*16 + ot)*64 + lane; elem = w[ot*16 + (lane&15)][kslab*32 + (lane>>4)*8 + j]
__global__ __launch_bounds__(NT)
void rbf_prepcw(const float* __restrict__ cen, const float* __restrict__ ls,
                const float* __restrict__ w,
                ushort* __restrict__ Ch, ushort* __restrict__ Cl,
                ushort* __restrict__ Wf, float2* __restrict__ ecs)
{
    __shared__ float red[4][16];
    const int b = blockIdx.x, t = threadIdx.x, lane = t & 63, wq = t >> 6;

    if (b < 32) {                      // ---- C panels ----
        const int panel = b;
        const int row = panel * 16 + (lane & 15);
        const int col = wq * 32 + (lane >> 4) * 8;
        const float* p = cen + (size_t)row * D + col;
        float4 v0 = *(const float4*)p, v1 = *(const float4*)(p + 4);
        float f[8] = {v0.x, v0.y, v0.z, v0.w, v1.x, v1.y, v1.z, v1.w};
        u16x8 h, l;
        float s = 0.f;
#pragma unroll
        for (int j = 0; j < 8; ++j) {
            s = fmaf(f[j], f[j], s);
            ushort hb = f2bf(f[j]);
            h[j] = hb;
            l[j] = f2bf(f[j] - bf2f(hb));
        }
        const size_t c = ((size_t)panel * 4 + wq) * 64 + lane;
        *(u16x8*)&Ch[c * 8] = h;
        *(u16x8*)&Cl[c * 8] = l;
        s += __shfl_xor(s, 16);
        s += __shfl_xor(s, 32);
        if (lane < 16) red[wq][lane] = s;
        __syncthreads();
        if (t < 16) {
            float sum = red[0][t] + red[1][t] + red[2][t] + red[3][t];
            int k = panel * 16 + t;
            float e = __expf(2.0f * ls[k]);
            ecs[k] = make_float2(NL2E * e, NL2E * e * sum);
        }
    } else {                           // ---- W blocks ----
        const int c0 = (b - 32) * NT + t;
        const int ln = c0 & 63, ot = (c0 >> 6) & 15, ks = c0 >> 10;
        const int o  = ot * 16 + (ln & 15);
        const int kb = ks * 32 + (ln >> 4) * 8;
        const float* p = w + (size_t)o * K + kb;
        float4 v0 = *(const float4*)p, v1 = *(const float4*)(p + 4);
        u16x8 h;
        h[0] = f2bf(v0.x); h[1] = f2bf(v0.y); h[2] = f2bf(v0.z); h[3] = f2bf(v0.w);
        h[4] = f2bf(v1.x); h[5] = f2bf(v1.y); h[6] = f2bf(v1.z); h[7] = f2bf(v1.w);
        *(u16x8*)&Wf[(size_t)c0 * 8] = h;
    }
}

// ================= main: R10 main8 + block-cooperative X conversion =================
// 16 rows/block, 8 waves (512 thr), wave = K-eighth (64 kernels).
// X converted ONCE per block (512 thr x 4 elems) into frag-ordered LDS scratch
// aliased onto Acc's first 8KB (staging ends before combine; barrier-separated).
// All oacc indices compile-time (rule #20).
__global__ __launch_bounds__(512, 2)   // 2 blocks/CU: 16 waves/CU, VGPR cap 128
void rbf_main8y(const float* __restrict__ x,
                const ushort* __restrict__ Ch, const ushort* __restrict__ Cl,
                const ushort* __restrict__ Wf, const float2* __restrict__ ecs,
                float* __restrict__ out)
{
    __shared__ float  Acc[4][16][O + 4];  // 66.6 KB (first 8KB aliased as X scratch)
    __shared__ ushort Ps[8][16][PP];      // 10.2 KB
    __shared__ float  Ls[8][16];          // 0.5 KB
    __shared__ float  xs2s[16];           // 64 B

    const int t = threadIdx.x, lane = t & 63, wv = t >> 6;   // wv 0..7
    const int l15 = lane & 15, l4 = lane >> 4;
    const int pan = blockIdx.x;
    const int nb  = pan * 16;

    // ---- cooperative X conversion: 512 threads x 4 fp32 elems -> frag-ordered LDS ----
    {
        ushort* XF = (ushort*)&Acc[0][0][0];   // [hi 2048 ushorts][lo 2048 ushorts]
        const int r  = t >> 5;                 // row 0..15
        const int cq = t & 31;                 // col quad 0..31
        const int c0 = cq * 4;
        float4 v = *(const float4*)(x + (size_t)(nb + r) * D + c0);
        float f[4] = {v.x, v.y, v.z, v.w};
        ushort4 hv, lv;
        float s = 0.f;
        {
            float* fp = f;
            ushort h0, h1, h2, h3;
            s = fmaf(fp[0], fp[0], s); h0 = f2bf(fp[0]);
            s = fmaf(fp[1], fp[1], s); h1 = f2bf(fp[1]);
            s = fmaf(fp[2], fp[2], s); h2 = f2bf(fp[2]);
            s = fmaf(fp[3], fp[3], s); h3 = f2bf(fp[3]);
            hv = make_ushort4(h0, h1, h2, h3);
            lv = make_ushort4(f2bf(fp[0] - bf2f(h0)), f2bf(fp[1] - bf2f(h1)),
                              f2bf(fp[2] - bf2f(h2)), f2bf(fp[3] - bf2f(h3)));
        }
        const int q   = c0 >> 5;            // 0..3
        const int sub = (c0 >> 3) & 3;      // 0..3
        const int lp  = sub * 16 + r;       // frag lane
        const int j0  = c0 & 7;             // 0 or 4
        *(ushort4*)&XF[(q * 64 + lp) * 8 + j0]        = hv;
        *(ushort4*)&XF[2048 + (q * 64 + lp) * 8 + j0] = lv;
        // row norm: reduce over the 32 contiguous lanes of this row (half-wave)
        s += __shfl_xor(s, 1);  s += __shfl_xor(s, 2);
        s += __shfl_xor(s, 4);  s += __shfl_xor(s, 8);
        s += __shfl_xor(s, 16);
        if (cq == 0) xs2s[r] = s;
    }
    __syncthreads();

    // each wave pulls its X fragments into registers
    s16x8 xh[4], xl[4];
    {
        const ushort* XF = (const ushort*)&Acc[0][0][0];
#pragma unroll
        for (int q = 0; q < 4; ++q) {
            xh[q] = *(const s16x8*)&XF[(q * 64 + lane) * 8];
            xl[q] = *(const s16x8*)&XF[2048 + (q * 64 + lane) * 8];
        }
    }
    const float xs2v = xs2s[l15];
    __syncthreads();   // all waves have their frags; Acc region now free for combine

    f32x4 oacc[16];
#pragma unroll
    for (int i = 0; i < 16; ++i) oacc[i] = (f32x4){0.f, 0.f, 0.f, 0.f};
    float Lp = 0.f;

    const int kw = wv * 64;   // wave's kernel base (K-eighth)

#pragma unroll
    for (int s = 0; s < 2; ++s) {
        const int kslab = (kw >> 5) + s;
        const ushort* wbase = &Wf[(((size_t)kslab * 16) * 64 + lane) * 8];

        // GEMM1 (swapped: A=C, B=X) + exp2, two 16-kernel tiles
#pragma unroll
        for (int bt = 0; bt < 2; ++bt) {
            const size_t kt16 = (size_t)(kw >> 4) + s * 2 + bt;
            s16x8 ch[4], cl[4];
#pragma unroll
            for (int q = 0; q < 4; ++q) {
                const size_t cc = ((kt16 * 4 + q) * 64 + lane) * 8;
                ch[q] = *(const s16x8*)&Ch[cc];
                cl[q] = *(const s16x8*)&Cl[cc];
            }
            f32x4 ghh = (f32x4){0.f,0.f,0.f,0.f};
            f32x4 ghl = (f32x4){0.f,0.f,0.f,0.f};
            f32x4 glh = (f32x4){0.f,0.f,0.f,0.f};
#pragma unroll
            for (int q = 0; q < 4; ++q) {
                ghh = __builtin_amdgcn_mfma_f32_16x16x32_bf16(ch[q], xh[q], ghh, 0, 0, 0);
                ghl = __builtin_amdgcn_mfma_f32_16x16x32_bf16(ch[q], xl[q], ghl, 0, 0, 0);
                glh = __builtin_amdgcn_mfma_f32_16x16x32_bf16(cl[q], xh[q], glh, 0, 0, 0);
            }
            f32x4 g = ghh + ghl + glh;

            const int kbase = kw + s * 32 + bt * 16 + l4 * 4;
            float4 e0 = *(const float4*)&ecs[kbase];
            float4 e1 = *(const float4*)&ecs[kbase + 2];
            float ph0 = exp2f(fmaf(e0.x, fmaf(-2.f, g[0], xs2v), e0.y));
            float ph1 = exp2f(fmaf(e0.z, fmaf(-2.f, g[1], xs2v), e0.w));
            float ph2 = exp2f(fmaf(e1.x, fmaf(-2.f, g[2], xs2v), e1.y));
            float ph3 = exp2f(fmaf(e1.z, fmaf(-2.f, g[3], xs2v), e1.w));
            Lp += (ph0 + ph1) + (ph2 + ph3);
            uint p0 = (uint)f2bf(ph0) | ((uint)f2bf(ph1) << 16);
            uint p1 = (uint)f2bf(ph2) | ((uint)f2bf(ph3) << 16);
            *(uint2*)&Ps[wv][l15][bt * 16 + l4 * 4] = make_uint2(p0, p1);
        }

        // wave-private transpose read (same-wave DS order, no barrier) + GEMM2
        s16x8 pa = *(const s16x8*)&Ps[wv][l15][l4 * 8];
#pragma unroll
        for (int ot = 0; ot < 16; ++ot) {
            s16x8 bfr = *(const s16x8*)&wbase[(size_t)ot * 64 * 8];
            oacc[ot] = __builtin_amdgcn_mfma_f32_16x16x32_bf16(pa, bfr, oacc[ot], 0, 0, 0);
        }
    }

    // per-wave row sums (over its 64 kernels)
    {
        float v = Lp;
        v += __shfl_xor(v, 16);
        v += __shfl_xor(v, 32);
        if (lane < 16) Ls[wv][lane] = v;
    }

    // ---- combine 8 wave partials: static 2-stage tree ----
    __syncthreads();   // ensure all X-frag reads done block-wide before Acc reuse
    if (wv < 4) {
#pragma unroll
        for (int ot = 0; ot < 16; ++ot)
#pragma unroll
            for (int r = 0; r < 4; ++r)
                Acc[wv][l4 * 4 + r][ot * 16 + l15] = oacc[ot][r];
    }
    __syncthreads();
    if (wv >= 4) {
#pragma unroll
        for (int ot = 0; ot < 16; ++ot)
#pragma unroll
            for (int r = 0; r < 4; ++r)
                Acc[wv - 4][l4 * 4 + r][ot * 16 + l15] += oacc[ot][r];
    }
    __syncthreads();

    // ---- store: sum 4 buffers + normalize; 512 thr, each 8 floats of one row ----
    {
        const int n  = t >> 5;          // 0..15
        const int c8 = (t & 31) * 8;
        float inv = 1.0f / (Ls[0][n] + Ls[1][n] + Ls[2][n] + Ls[3][n] +
                            Ls[4][n] + Ls[5][n] + Ls[6][n] + Ls[7][n] + 1e-9f);
        float4 a0 = *(const float4*)&Acc[0][n][c8];
        float4 b0 = *(const float4*)&Acc[1][n][c8];
        float4 c0 = *(const float4*)&Acc[2][n][c8];
        float4 d0 = *(const float4*)&Acc[3][n][c8];
        float4 a1 = *(const float4*)&Acc[0][n][c8 + 4];
        float4 b1 = *(const float4*)&Acc[1][n][c8 + 4];
        float4 c1 = *(const float4*)&Acc[2][n][c8 + 4];
        float4 d1 = *(const float4*)&Acc[3][n][c8 + 4];
        float4 o0, o1;
        o0.x = ((a0.x + b0.x) + (c0.x + d0.x)) * inv;
        o0.y = ((a0.y + b0.y) + (c0.y + d0.y)) * inv;
        o0.z = ((a0.z + b0.z) + (c0.z + d0.z)) * inv;
        o0.w = ((a0.w + b0.w) + (c0.w + d0.w)) * inv;
        o1.x = ((a1.x + b1.x) + (c1.x + d1.x)) * inv;
        o1.y = ((a1.y + b1.y) + (c1.y + d1.y)) * inv;
        o1.z = ((a1.z + b1.z) + (c1.z + d1.z)) * inv;
        o1.w = ((a1.w + b1.w) + (c1.w + d1.w)) * inv;
        float* po = &out[(size_t)(nb + n) * O + c8];
        *(float4*)po = o0;
        *(float4*)(po + 4) = o1;
    }
}

// ================= fallback (round-4 kernel, known-pass, no ws) =================
__global__ __launch_bounds__(NT, 2)
void rbf_fb(const float* __restrict__ x, const float* __restrict__ cen,
            const float* __restrict__ ls, const float* __restrict__ w,
            float* __restrict__ out)
{
    __shared__ ushort Ps2[2][4][16][PP];
    __shared__ float  Acc2[2][16][O + 4];
    __shared__ float  Ls2[4][16];
    const int t = threadIdx.x, lane = t & 63, wv = t >> 6;
    const int l15 = lane & 15, l4 = lane >> 4;
    const int nb = blockIdx.x * 16;

    s16x8 xh[4], xl[4];
    float sx = 0.f;
    {
        const float* xr = x + (size_t)(nb + l15) * D;
#pragma unroll
        for (int q = 0; q < 4; ++q) {
            float4 v0 = *(const float4*)(xr + q * 32 + l4 * 8);
            float4 v1 = *(const float4*)(xr + q * 32 + l4 * 8 + 4);
            float f[8] = {v0.x, v0.y, v0.z, v0.w, v1.x, v1.y, v1.z, v1.w};
            s16x8 hh, lo;
#pragma unroll
            for (int j = 0; j < 8; ++j) {
                sx = fmaf(f[j], f[j], sx);
                ushort hb = f2bf(f[j]);
                hh[j] = (short)hb; lo[j] = (short)f2bf(f[j] - bf2f(hb));
            }
            xh[q] = hh; xl[q] = lo;
        }
    }
    sx += __shfl_xor(sx, 16); sx += __shfl_xor(sx, 32);
    float xs2v[4];
#pragma unroll
    for (int r = 0; r < 4; ++r) xs2v[r] = __shfl(sx, l4 * 4 + r);

    f32x4 oacc[16];
#pragma unroll
    for (int ot = 0; ot < 16; ++ot) oacc[ot] = (f32x4){0.f,0.f,0.f,0.f};
    float Lp[4] = {0.f,0.f,0.f,0.f};
    const int kq = wv * (K / 4);

#pragma unroll
    for (int s = 0; s < 4; ++s) {
        const int k0 = kq + s * 32;
#pragma unroll
        for (int bt = 0; bt < 2; ++bt) {
            const int kk = k0 + bt * 16 + l15;
            const float* cr = cen + (size_t)kk * D;
            s16x8 ch[4], cl[4];
            float sc = 0.f;
#pragma unroll
            for (int q = 0; q < 4; ++q) {
                float4 v0 = *(const float4*)(cr + q * 32 + l4 * 8);
                float4 v1 = *(const float4*)(cr + q * 32 + l4 * 8 + 4);
                float f[8] = {v0.x, v0.y, v0.z, v0.w, v1.x, v1.y, v1.z, v1.w};
                s16x8 hh, lo;
#pragma unroll
                for (int j = 0; j < 8; ++j) {
                    sc = fmaf(f[j], f[j], sc);
                    ushort hb = f2bf(f[j]);
                    hh[j] = (short)hb; lo[j] = (short)f2bf(f[j] - bf2f(hb));
                }
                ch[q] = hh; cl[q] = lo;
            }
            sc += __shfl_xor(sc, 16); sc += __shfl_xor(sc, 32);
            float es_ = __expf(2.0f * ls[kk]);
            f32x4 ghh={0,0,0,0}, ghl={0,0,0,0}, glh={0,0,0,0};
#pragma unroll
            for (int q = 0; q < 4; ++q) {
                ghh = __builtin_amdgcn_mfma_f32_16x16x32_bf16(xh[q], ch[q], ghh, 0,0,0);
                ghl = __builtin_amdgcn_mfma_f32_16x16x32_bf16(xh[q], cl[q], ghl, 0,0,0);
                glh = __builtin_amdgcn_mfma_f32_16x16x32_bf16(xl[q], ch[q], glh, 0,0,0);
            }
            f32x4 gg = ghh + ghl + glh;
#pragma unroll
            for (int r = 0; r < 4; ++r) {
                float r2 = xs2v[r] + sc - 2.0f * gg[r];
                float ph = __expf(-es_ * r2);
                Lp[r] += ph;
                Ps2[s & 1][wv][l4 * 4 + r][bt * 16 + l15] = f2bf(ph);
            }
        }
        s16x8 pa = *(const s16x8*)&Ps2[s & 1][wv][l15][l4 * 8];
#pragma unroll
        for (int ot = 0; ot < 16; ++ot) {
            const float* wr = w + (size_t)(ot * 16 + l15) * K + k0;
            float4 v0 = *(const float4*)(wr + l4 * 8);
            float4 v1 = *(const float4*)(wr + l4 * 8 + 4);
            s16x8 bb;
            bb[0]=(short)f2bf(v0.x); bb[1]=(short)f2bf(v0.y); bb[2]=(short)f2bf(v0.z); bb[3]=(short)f2bf(v0.w);
            bb[4]=(short)f2bf(v1.x); bb[5]=(short)f2bf(v1.y); bb[6]=(short)f2bf(v1.z); bb[7]=(short)f2bf(v1.w);
            oacc[ot] = __builtin_amdgcn_mfma_f32_16x16x32_bf16(pa, bb, oacc[ot], 0,0,0);
        }
    }
#pragma unroll
    for (int r = 0; r < 4; ++r) {
        float v = Lp[r];
        v += __shfl_xor(v, 1); v += __shfl_xor(v, 2);
        v += __shfl_xor(v, 4); v += __shfl_xor(v, 8);
        if (l15 == 0) Ls2[wv][l4 * 4 + r] = v;
    }
    if (wv < 2) {
#pragma unroll
        for (int ot = 0; ot < 16; ++ot)
#pragma unroll
            for (int r = 0; r < 4; ++r)
                Acc2[wv][l4 * 4 + r][ot * 16 + l15] = oacc[ot][r];
    }
    __syncthreads();
    if (wv >= 2) {
#pragma unroll
        for (int ot = 0; ot < 16; ++ot)
#pragma unroll
            for (int r = 0; r < 4; ++r)
                Acc2[wv - 2][l4 * 4 + r][ot * 16 + l15] += oacc[ot][r];
    }
    __syncthreads();
#pragma unroll
    for (int rr = 0; rr < 4; ++rr) {
        const int n = wv * 4 + rr;
        float inv = 1.0f / (Ls2[0][n] + Ls2[1][n] + Ls2[2][n] + Ls2[3][n] + 1e-9f);
        float4 a0 = *(const float4*)&Acc2[0][n][lane * 4];
        float4 a1 = *(const float4*)&Acc2[1][n][lane * 4];
        float4 o4;
        o4.x = (a0.x + a1.x) * inv; o4.y = (a0.y + a1.y) * inv;
        o4.z = (a0.z + a1.z) * inv; o4.w = (a0.w + a1.w) * inv;
        *(float4*)&out[(size_t)(nb + n) * O + lane * 4] = o4;
    }
}

extern "C" void kernel_launch(void* const* d_in, const int* in_sizes, int n_in,
                              void* d_out, int out_size, void* d_ws, size_t ws_size,
                              hipStream_t stream) {
    const float* x   = (const float*)d_in[0];  // N x 128
    const float* cen = (const float*)d_in[1];  // 512 x 128
    const float* ls  = (const float*)d_in[2];  // 512
    const float* w   = (const float*)d_in[3];  // 256 x 512
    float* out = (float*)d_out;                // N x 256
    const int N = in_sizes[0] / D;             // 8192

    size_t oCh = 0;
    size_t oCl = oCh + (size_t)K * D * 2;
    size_t oWf = oCl + (size_t)K * D * 2;
    size_t oec = oWf + (size_t)O * K * 2;
    size_t need = oec + (size_t)K * 8;

    if (ws_size < need || (N % 16) != 0) {
        dim3 grid(N / 16), block(NT);
        hipLaunchKernelGGL(rbf_fb, grid, block, 0, stream, x, cen, ls, w, out);
        return;
    }

    char* ws = (char*)d_ws;
    ushort* Ch = (ushort*)(ws + oCh);
    ushort* Cl = (ushort*)(ws + oCl);
    ushort* Wf = (ushort*)(ws + oWf);
    float2* ecs = (float2*)(ws + oec);

    // prep: 32 C panels + 64 W blocks = 96 blocks
    dim3 pgrid(32 + (O * K / 8) / NT), pblock(NT);
    hipLaunchKernelGGL(rbf_prepcw, pgrid, pblock, 0, stream,
                       cen, ls, w, Ch, Cl, Wf, ecs);

    dim3 grid(N / 16), block(512);
    hipLaunchKernelGGL(rbf_main8y, grid, block, 0, stream,
                       x, Ch, Cl, Wf, ecs, out);
}

// Round 16
// 26.954 us; speedup vs baseline: 2.4581x; 1.0703x over previous
//
#include <hip/hip_runtime.h>

typedef float  f32x4 __attribute__((ext_vector_type(4)));
typedef short  s16x8 __attribute__((ext_vector_type(8)));
typedef ushort u16x8 __attribute__((ext_vector_type(8)));

constexpr int D  = 128;
constexpr int K  = 512;
constexpr int O  = 256;
constexpr int NT = 256;
constexpr float NL2E = -1.44269504088896340736f;  // -log2(e)
constexpr int PP = 40;   // Ps row stride in ushorts

__device__ __forceinline__ ushort f2bf(float f) {
    uint u = __builtin_bit_cast(uint, f);
    return (ushort)((u + 0x7FFFu + ((u >> 16) & 1u)) >> 16);
}
__device__ __forceinline__ float bf2f(ushort h) {
    return __builtin_bit_cast(float, ((uint)h) << 16);
}

// ================= prep: fragment-ordered bf16 operands + fused stats =================
// chunk layout: chunk c holds 64 lanes x 8 bf16 (16B/lane, contiguous 1KB).
// X/C: c = (panel16*4 + q)*64 + lane ; elem = src[panel*16 + (lane&15)][q*32 + (lane>>4)*8 + j]
// W:   c = (kslab32*16 + ot)*64 + lane; elem = w[ot*16 + (lane&15)][kslab*32 + (lane>>4)*8 + j]
__global__ __launch_bounds__(NT)
void rbf_prep(const float* __restrict__ x, const float* __restrict__ cen,
              const float* __restrict__ ls, const float* __restrict__ w,
              ushort* __restrict__ Xh, ushort* __restrict__ Xl,
              ushort* __restrict__ Ch, ushort* __restrict__ Cl,
              ushort* __restrict__ Wf, float* __restrict__ xs2,
              float2* __restrict__ ecs, int nxb, int ncb)
{
    __shared__ float red[4][16];
    const int b = blockIdx.x, t = threadIdx.x, lane = t & 63, wq = t >> 6;

    if (b < nxb + ncb) {
        const bool isX  = b < nxb;
        const int panel = isX ? b : (b - nxb);
        const float* src = isX ? x : cen;
        ushort* dh = isX ? Xh : Ch;
        ushort* dl = isX ? Xl : Cl;
        const int row = panel * 16 + (lane & 15);
        const int col = wq * 32 + (lane >> 4) * 8;
        const float* p = src + (size_t)row * D + col;
        float4 v0 = *(const float4*)p, v1 = *(const float4*)(p + 4);
        float f[8] = {v0.x, v0.y, v0.z, v0.w, v1.x, v1.y, v1.z, v1.w};
        u16x8 h, l;
        float s = 0.f;
#pragma unroll
        for (int j = 0; j < 8; ++j) {
            s = fmaf(f[j], f[j], s);
            ushort hb = f2bf(f[j]);
            h[j] = hb;
            l[j] = f2bf(f[j] - bf2f(hb));
        }
        const size_t c = ((size_t)panel * 4 + wq) * 64 + lane;
        *(u16x8*)&dh[c * 8] = h;
        *(u16x8*)&dl[c * 8] = l;
        s += __shfl_xor(s, 16);
        s += __shfl_xor(s, 32);
        if (lane < 16) red[wq][lane] = s;
        __syncthreads();
        if (t < 16) {
            float sum = red[0][t] + red[1][t] + red[2][t] + red[3][t];
            if (isX) {
                xs2[panel * 16 + t] = sum;
            } else {
                int k = panel * 16 + t;
                float e = __expf(2.0f * ls[k]);
                ecs[k] = make_float2(NL2E * e, NL2E * e * sum);
            }
        }
    } else {
        const int c0 = (b - nxb - ncb) * NT + t;
        const int ln = c0 & 63, ot = (c0 >> 6) & 15, ks = c0 >> 10;
        const int o  = ot * 16 + (ln & 15);
        const int kb = ks * 32 + (ln >> 4) * 8;
        const float* p = w + (size_t)o * K + kb;
        float4 v0 = *(const float4*)p, v1 = *(const float4*)(p + 4);
        u16x8 h;
        h[0] = f2bf(v0.x); h[1] = f2bf(v0.y); h[2] = f2bf(v0.z); h[3] = f2bf(v0.w);
        h[4] = f2bf(v1.x); h[5] = f2bf(v1.y); h[6] = f2bf(v1.z); h[7] = f2bf(v1.w);
        *(u16x8*)&Wf[(size_t)c0 * 8] = h;
    }
}

// ================= main: R10 main8 + per-block phase rotation =================
// 16 rows/block, 8 waves (512 thr), wave = K-eighth (64 kernels).
// NEW vs R10: each block visits its slabs/tiles in a phase-rotated order
// (se = s^b0, bte = bt^b1, phase from blockIdx) so concurrently-running blocks
// touch DIFFERENT C/W regions -> breaks the 64-way same-line L2 fan-in of the
// lockstep stream. Addresses and LDS columns only; all register indices static.
__global__ __launch_bounds__(512, 2)   // 2 blocks/CU: 16 waves/CU, VGPR cap 128
void rbf_main8(const ushort* __restrict__ Xh, const ushort* __restrict__ Xl,
               const ushort* __restrict__ Ch, const ushort* __restrict__ Cl,
               const ushort* __restrict__ Wf, const float* __restrict__ xs2,
               const float2* __restrict__ ecs, float* __restrict__ out, int N)
{
    __shared__ ushort Ps[8][16][PP];      // 10.2 KB, per-wave private
    __shared__ float  Acc[4][16][O + 4];  // 66.6 KB
    __shared__ float  Ls[8][16];          // 0.5 KB

    const int t = threadIdx.x, lane = t & 63, wv = t >> 6;   // wv 0..7
    const int l15 = lane & 15, l4 = lane >> 4;
    const int pan = blockIdx.x;
    const int phase = ((pan >> 3) ^ pan) & 3;   // decorrelation phase
    const int pb0 = phase & 1, pb1 = (phase >> 1) & 1;

    // X fragments (frag-ordered -> base + lane*16B); same 16 rows for all waves
    s16x8 xh[4], xl[4];
    {
        const size_t base = ((size_t)pan * 4) * 64 + lane;
#pragma unroll
        for (int q = 0; q < 4; ++q) {
            xh[q] = *(const s16x8*)&Xh[(base + q * 64) * 8];
            xl[q] = *(const s16x8*)&Xl[(base + q * 64) * 8];
        }
    }
    const float xs2v = xs2[pan * 16 + l15];

    f32x4 oacc[16];
#pragma unroll
    for (int i = 0; i < 16; ++i) oacc[i] = (f32x4){0.f, 0.f, 0.f, 0.f};
    float Lp = 0.f;

    const int kw = wv * 64;   // wave's kernel base (K-eighth)

#pragma unroll
    for (int s = 0; s < 2; ++s) {
        const int se = s ^ pb0;                  // rotated slab order
        const int kslab = (kw >> 5) + se;
        const ushort* wbase = &Wf[(((size_t)kslab * 16) * 64 + lane) * 8];

        // GEMM1 (swapped: A=C, B=X) + exp2, two 16-kernel tiles (rotated order)
#pragma unroll
        for (int bt = 0; bt < 2; ++bt) {
            const int bte = bt ^ pb1;            // rotated tile order within slab
            const size_t kt16 = (size_t)(kw >> 4) + se * 2 + bte;
            s16x8 ch[4], cl[4];
#pragma unroll
            for (int q = 0; q < 4; ++q) {
                const size_t cc = ((kt16 * 4 + q) * 64 + lane) * 8;
                ch[q] = *(const s16x8*)&Ch[cc];
                cl[q] = *(const s16x8*)&Cl[cc];
            }
            f32x4 ghh = (f32x4){0.f,0.f,0.f,0.f};
            f32x4 ghl = (f32x4){0.f,0.f,0.f,0.f};
            f32x4 glh = (f32x4){0.f,0.f,0.f,0.f};
#pragma unroll
            for (int q = 0; q < 4; ++q) {
                ghh = __builtin_amdgcn_mfma_f32_16x16x32_bf16(ch[q], xh[q], ghh, 0, 0, 0);
                ghl = __builtin_amdgcn_mfma_f32_16x16x32_bf16(ch[q], xl[q], ghl, 0, 0, 0);
                glh = __builtin_amdgcn_mfma_f32_16x16x32_bf16(cl[q], xh[q], glh, 0, 0, 0);
            }
            f32x4 g = ghh + ghl + glh;

            const int kbase = kw + se * 32 + bte * 16 + l4 * 4;
            float4 e0 = *(const float4*)&ecs[kbase];
            float4 e1 = *(const float4*)&ecs[kbase + 2];
            float ph0 = exp2f(fmaf(e0.x, fmaf(-2.f, g[0], xs2v), e0.y));
            float ph1 = exp2f(fmaf(e0.z, fmaf(-2.f, g[1], xs2v), e0.w));
            float ph2 = exp2f(fmaf(e1.x, fmaf(-2.f, g[2], xs2v), e1.y));
            float ph3 = exp2f(fmaf(e1.z, fmaf(-2.f, g[3], xs2v), e1.w));
            Lp += (ph0 + ph1) + (ph2 + ph3);
            uint p0 = (uint)f2bf(ph0) | ((uint)f2bf(ph1) << 16);
            uint p1 = (uint)f2bf(ph2) | ((uint)f2bf(ph3) << 16);
            *(uint2*)&Ps[wv][l15][bte * 16 + l4 * 4] = make_uint2(p0, p1);
        }

        // wave-private transpose read (same-wave DS order, no barrier) + GEMM2
        s16x8 pa = *(const s16x8*)&Ps[wv][l15][l4 * 8];
#pragma unroll
        for (int ot = 0; ot < 16; ++ot) {
            s16x8 bfr = *(const s16x8*)&wbase[(size_t)ot * 64 * 8];
            oacc[ot] = __builtin_amdgcn_mfma_f32_16x16x32_bf16(pa, bfr, oacc[ot], 0, 0, 0);
        }
    }

    // per-wave row sums (over its 64 kernels)
    {
        float v = Lp;
        v += __shfl_xor(v, 16);
        v += __shfl_xor(v, 32);
        if (lane < 16) Ls[wv][lane] = v;
    }

    // ---- combine 8 wave partials: static 2-stage tree ----
    if (wv < 4) {
#pragma unroll
        for (int ot = 0; ot < 16; ++ot)
#pragma unroll
            for (int r = 0; r < 4; ++r)
                Acc[wv][l4 * 4 + r][ot * 16 + l15] = oacc[ot][r];
    }
    __syncthreads();
    if (wv >= 4) {
#pragma unroll
        for (int ot = 0; ot < 16; ++ot)
#pragma unroll
            for (int r = 0; r < 4; ++r)
                Acc[wv - 4][l4 * 4 + r][ot * 16 + l15] += oacc[ot][r];
    }
    __syncthreads();

    // ---- store: sum 4 buffers + normalize; 512 thr, each 8 floats of one row ----
    {
        const int n  = t >> 5;          // 0..15
        const int c8 = (t & 31) * 8;
        float inv = 1.0f / (Ls[0][n] + Ls[1][n] + Ls[2][n] + Ls[3][n] +
                            Ls[4][n] + Ls[5][n] + Ls[6][n] + Ls[7][n] + 1e-9f);
        float4 a0 = *(const float4*)&Acc[0][n][c8];
        float4 b0 = *(const float4*)&Acc[1][n][c8];
        float4 c0 = *(const float4*)&Acc[2][n][c8];
        float4 d0 = *(const float4*)&Acc[3][n][c8];
        float4 a1 = *(const float4*)&Acc[0][n][c8 + 4];
        float4 b1 = *(const float4*)&Acc[1][n][c8 + 4];
        float4 c1 = *(const float4*)&Acc[2][n][c8 + 4];
        float4 d1 = *(const float4*)&Acc[3][n][c8 + 4];
        float4 o0, o1;
        o0.x = ((a0.x + b0.x) + (c0.x + d0.x)) * inv;
        o0.y = ((a0.y + b0.y) + (c0.y + d0.y)) * inv;
        o0.z = ((a0.z + b0.z) + (c0.z + d0.z)) * inv;
        o0.w = ((a0.w + b0.w) + (c0.w + d0.w)) * inv;
        o1.x = ((a1.x + b1.x) + (c1.x + d1.x)) * inv;
        o1.y = ((a1.y + b1.y) + (c1.y + d1.y)) * inv;
        o1.z = ((a1.z + b1.z) + (c1.z + d1.z)) * inv;
        o1.w = ((a1.w + b1.w) + (c1.w + d1.w)) * inv;
        float* po = &out[(size_t)(pan * 16 + n) * O + c8];
        *(float4*)po = o0;
        *(float4*)(po + 4) = o1;
    }
}

// ================= fallback (round-4 kernel, known-pass, no ws) =================
__global__ __launch_bounds__(NT, 2)
void rbf_fb(const float* __restrict__ x, const float* __restrict__ cen,
            const float* __restrict__ ls, const float* __restrict__ w,
            float* __restrict__ out)
{
    __shared__ ushort Ps2[2][4][16][PP];
    __shared__ float  Acc2[2][16][O + 4];
    __shared__ float  Ls2[4][16];
    const int t = threadIdx.x, lane = t & 63, wv = t >> 6;
    const int l15 = lane & 15, l4 = lane >> 4;
    const int nb = blockIdx.x * 16;

    s16x8 xh[4], xl[4];
    float sx = 0.f;
    {
        const float* xr = x + (size_t)(nb + l15) * D;
#pragma unroll
        for (int q = 0; q < 4; ++q) {
            float4 v0 = *(const float4*)(xr + q * 32 + l4 * 8);
            float4 v1 = *(const float4*)(xr + q * 32 + l4 * 8 + 4);
            float f[8] = {v0.x, v0.y, v0.z, v0.w, v1.x, v1.y, v1.z, v1.w};
            s16x8 hh, lo;
#pragma unroll
            for (int j = 0; j < 8; ++j) {
                sx = fmaf(f[j], f[j], sx);
                ushort hb = f2bf(f[j]);
                hh[j] = (short)hb; lo[j] = (short)f2bf(f[j] - bf2f(hb));
            }
            xh[q] = hh; xl[q] = lo;
        }
    }
    sx += __shfl_xor(sx, 16); sx += __shfl_xor(sx, 32);
    float xs2v[4];
#pragma unroll
    for (int r = 0; r < 4; ++r) xs2v[r] = __shfl(sx, l4 * 4 + r);

    f32x4 oacc[16];
#pragma unroll
    for (int ot = 0; ot < 16; ++ot) oacc[ot] = (f32x4){0.f,0.f,0.f,0.f};
    float Lp[4] = {0.f,0.f,0.f,0.f};
    const int kq = wv * (K / 4);

#pragma unroll
    for (int s = 0; s < 4; ++s) {
        const int k0 = kq + s * 32;
#pragma unroll
        for (int bt = 0; bt < 2; ++bt) {
            const int kk = k0 + bt * 16 + l15;
            const float* cr = cen + (size_t)kk * D;
            s16x8 ch[4], cl[4];
            float sc = 0.f;
#pragma unroll
            for (int q = 0; q < 4; ++q) {
                float4 v0 = *(const float4*)(cr + q * 32 + l4 * 8);
                float4 v1 = *(const float4*)(cr + q * 32 + l4 * 8 + 4);
                float f[8] = {v0.x, v0.y, v0.z, v0.w, v1.x, v1.y, v1.z, v1.w};
                s16x8 hh, lo;
#pragma unroll
                for (int j = 0; j < 8; ++j) {
                    sc = fmaf(f[j], f[j], sc);
                    ushort hb = f2bf(f[j]);
                    hh[j] = (short)hb; lo[j] = (short)f2bf(f[j] - bf2f(hb));
                }
                ch[q] = hh; cl[q] = lo;
            }
            sc += __shfl_xor(sc, 16); sc += __shfl_xor(sc, 32);
            float es_ = __expf(2.0f * ls[kk]);
            f32x4 ghh={0,0,0,0}, ghl={0,0,0,0}, glh={0,0,0,0};
#pragma unroll
            for (int q = 0; q < 4; ++q) {
                ghh = __builtin_amdgcn_mfma_f32_16x16x32_bf16(xh[q], ch[q], ghh, 0,0,0);
                ghl = __builtin_amdgcn_mfma_f32_16x16x32_bf16(xh[q], cl[q], ghl, 0,0,0);
                glh = __builtin_amdgcn_mfma_f32_16x16x32_bf16(xl[q], ch[q], glh, 0,0,0);
            }
            f32x4 gg = ghh + ghl + glh;
#pragma unroll
            for (int r = 0; r < 4; ++r) {
                float r2 = xs2v[r] + sc - 2.0f * gg[r];
                float ph = __expf(-es_ * r2);
                Lp[r] += ph;
                Ps2[s & 1][wv][l4 * 4 + r][bt * 16 + l15] = f2bf(ph);
            }
        }
        s16x8 pa = *(const s16x8*)&Ps2[s & 1][wv][l15][l4 * 8];
#pragma unroll
        for (int ot = 0; ot < 16; ++ot) {
            const float* wr = w + (size_t)(ot * 16 + l15) * K + k0;
            float4 v0 = *(const float4*)(wr + l4 * 8);
            float4 v1 = *(const float4*)(wr + l4 * 8 + 4);
            s16x8 bb;
            bb[0]=(short)f2bf(v0.x); bb[1]=(short)f2bf(v0.y); bb[2]=(short)f2bf(v0.z); bb[3]=(short)f2bf(v0.w);
            bb[4]=(short)f2bf(v1.x); bb[5]=(short)f2bf(v1.y); bb[6]=(short)f2bf(v1.z); bb[7]=(short)f2bf(v1.w);
            oacc[ot] = __builtin_amdgcn_mfma_f32_16x16x32_bf16(pa, bb, oacc[ot], 0,0,0);
        }
    }
#pragma unroll
    for (int r = 0; r < 4; ++r) {
        float v = Lp[r];
        v += __shfl_xor(v, 1); v += __shfl_xor(v, 2);
        v += __shfl_xor(v, 4); v += __shfl_xor(v, 8);
        if (l15 == 0) Ls2[wv][l4 * 4 + r] = v;
    }
    if (wv < 2) {
#pragma unroll
        for (int ot = 0; ot < 16; ++ot)
#pragma unroll
            for (int r = 0; r < 4; ++r)
                Acc2[wv][l4 * 4 + r][ot * 16 + l15] = oacc[ot][r];
    }
    __syncthreads();
    if (wv >= 2) {
#pragma unroll
        for (int ot = 0; ot < 16; ++ot)
#pragma unroll
            for (int r = 0; r < 4; ++r)
                Acc2[wv - 2][l4 * 4 + r][ot * 16 + l15] += oacc[ot][r];
    }
    __syncthreads();
#pragma unroll
    for (int rr = 0; rr < 4; ++rr) {
        const int n = wv * 4 + rr;
        float inv = 1.0f / (Ls2[0][n] + Ls2[1][n] + Ls2[2][n] + Ls2[3][n] + 1e-9f);
        float4 a0 = *(const float4*)&Acc2[0][n][lane * 4];
        float4 a1 = *(const float4*)&Acc2[1][n][lane * 4];
        float4 o4;
        o4.x = (a0.x + a1.x) * inv; o4.y = (a0.y + a1.y) * inv;
        o4.z = (a0.z + a1.z) * inv; o4.w = (a0.w + a1.w) * inv;
        *(float4*)&out[(size_t)(nb + n) * O + lane * 4] = o4;
    }
}

extern "C" void kernel_launch(void* const* d_in, const int* in_sizes, int n_in,
                              void* d_out, int out_size, void* d_ws, size_t ws_size,
                              hipStream_t stream) {
    const float* x   = (const float*)d_in[0];  // N x 128
    const float* cen = (const float*)d_in[1];  // 512 x 128
    const float* ls  = (const float*)d_in[2];  // 512
    const float* w   = (const float*)d_in[3];  // 256 x 512
    float* out = (float*)d_out;                // N x 256
    const int N = in_sizes[0] / D;             // 8192

    size_t oXh = 0;
    size_t oXl = oXh + (size_t)N * D * 2;
    size_t oCh = oXl + (size_t)N * D * 2;
    size_t oCl = oCh + (size_t)K * D * 2;
    size_t oWf = oCl + (size_t)K * D * 2;
    size_t oxs = oWf + (size_t)O * K * 2;
    size_t oec = oxs + (size_t)N * 4;
    size_t need = oec + (size_t)K * 8;

    if (ws_size < need || (N % 16) != 0) {
        dim3 grid(N / 16), block(NT);
        hipLaunchKernelGGL(rbf_fb, grid, block, 0, stream, x, cen, ls, w, out);
        return;
    }

    char* ws = (char*)d_ws;
    ushort* Xh = (ushort*)(ws + oXh);
    ushort* Xl = (ushort*)(ws + oXl);
    ushort* Ch = (ushort*)(ws + oCh);
    ushort* Cl = (ushort*)(ws + oCl);
    ushort* Wf = (ushort*)(ws + oWf);
    float*  xs2 = (float*)(ws + oxs);
    float2* ecs = (float2*)(ws + oec);

    const int nxb = N / 16;                    // X panels
    const int ncb = K / 16;                    // C panels
    const int nwb = (O * K / 8) / NT;          // W blocks
    dim3 pgrid(nxb + ncb + nwb), pblock(NT);
    hipLaunchKernelGGL(rbf_prep, pgrid, pblock, 0, stream,
                       x, cen, ls, w, Xh, Xl, Ch, Cl, Wf, xs2, ecs, nxb, ncb);

    dim3 grid(N / 16), block(512);
    hipLaunchKernelGGL(rbf_main8, grid, block, 0, stream,
                       Xh, Xl, Ch, Cl, Wf, xs2, ecs, out, N);
}